// Round 1
// baseline (1938.125 us; speedup 1.0000x reference)
//
#include <hip/hip_runtime.h>
#include <math.h>

#define NEG_SLOPE 0.2f
#define LRELU(v) ((v) > 0.f ? (v) : NEG_SLOPE * (v))

// order-preserving float<->uint punning so atomicMax(unsigned) == float max.
// encode: nonneg -> bits|0x80000000 ; neg -> ~bits.  0u is below every real
// encoding, so memset(0) is the max-identity (every node has a self-loop, so
// every m slot gets written by at least one real edge).
__device__ __forceinline__ unsigned f2ord(float f) {
    unsigned b = __float_as_uint(f);
    return (b & 0x80000000u) ? ~b : (b | 0x80000000u);
}
__device__ __forceinline__ float ord2f(unsigned u) {
    return (u & 0x80000000u) ? __uint_as_float(u ^ 0x80000000u)
                             : __uint_as_float(~u);
}

// ---------------- layer 1 ----------------

// h1[n][64] = x[n][128] @ W1[128][64]; thread per (n,col)
__global__ void k_gemm1(const float* __restrict__ x, const float* __restrict__ W,
                        float* __restrict__ h1, int N) {
    int t = blockIdx.x * 256 + threadIdx.x;
    if (t >= N * 64) return;
    int n = t >> 6, col = t & 63;
    const float* xr = x + (size_t)n * 128;
    float acc = 0.f;
#pragma unroll
    for (int k = 0; k < 128; ++k) acc = fmaf(xr[k], W[k * 64 + col], acc);
    h1[t] = acc;
}

// alpha_src[n][h], alpha_dst[n][h]; thread per (n,h)
__global__ void k_alpha1(const float* __restrict__ h1, const float* __restrict__ a_src,
                         const float* __restrict__ a_dst, float* __restrict__ asrc,
                         float* __restrict__ adst, int N) {
    int t = blockIdx.x * 256 + threadIdx.x;
    if (t >= N * 8) return;
    int n = t >> 3, h = t & 7;
    const float* hp = h1 + (size_t)n * 64 + h * 8;
    const float* as = a_src + h * 8;
    const float* ad = a_dst + h * 8;
    float s = 0.f, d = 0.f;
#pragma unroll
    for (int c = 0; c < 8; ++c) {
        float hv = hp[c];
        s = fmaf(hv, as[c], s);
        d = fmaf(hv, ad[c], d);
    }
    asrc[t] = s;
    adst[t] = d;
}

// segment max over dst; thread per (edge,head)
__global__ void k_edge_max1(const int* __restrict__ src, const int* __restrict__ dst,
                            int E, int ET,
                            const float* __restrict__ asrc, const float* __restrict__ adst,
                            unsigned* __restrict__ m1) {
    int t = blockIdx.x * 256 + threadIdx.x;
    if (t >= ET * 8) return;
    int e = t >> 3, h = t & 7;
    int s, d;
    if (e < E) { s = src[e]; d = dst[e]; } else { s = d = e - E; }
    float v = asrc[s * 8 + h] + adst[d * 8 + h];
    v = LRELU(v);
    atomicMax(&m1[d * 8 + h], f2ord(v));
}

// denom = segment_sum exp(e - m[dst]); thread per (edge,head)
__global__ void k_edge_sum1(const int* __restrict__ src, const int* __restrict__ dst,
                            int E, int ET,
                            const float* __restrict__ asrc, const float* __restrict__ adst,
                            const unsigned* __restrict__ m1, float* __restrict__ denom) {
    int t = blockIdx.x * 256 + threadIdx.x;
    if (t >= ET * 8) return;
    int e = t >> 3, h = t & 7;
    int s, d;
    if (e < E) { s = src[e]; d = dst[e]; } else { s = d = e - E; }
    float v = asrc[s * 8 + h] + adst[d * 8 + h];
    v = LRELU(v);
    float m = ord2f(m1[d * 8 + h]);
    atomicAdd(&denom[d * 8 + h], __expf(v - m));
}

// out[dst] += h1[src] * alpha ; ONE WAVE PER EDGE, lane = channel (64)
__global__ void k_edge_agg1(const int* __restrict__ src, const int* __restrict__ dst,
                            int E, int ET,
                            const float* __restrict__ asrc, const float* __restrict__ adst,
                            const unsigned* __restrict__ m1, const float* __restrict__ denom,
                            const float* __restrict__ h1, float* __restrict__ agg) {
    int w = (int)((blockIdx.x * 256 + threadIdx.x) >> 6);
    if (w >= ET) return;
    int lane = threadIdx.x & 63;
    int s, d;
    if (w < E) { s = src[w]; d = dst[w]; } else { s = d = w - E; }
    int h = lane >> 3;
    float v = asrc[s * 8 + h] + adst[d * 8 + h];
    v = LRELU(v);
    float alpha = __expf(v - ord2f(m1[d * 8 + h])) / (denom[d * 8 + h] + 1e-16f);
    float msg = h1[(size_t)s * 64 + lane] * alpha;
    atomicAdd(&agg[(size_t)d * 64 + lane], msg);
}

// out1 = elu(agg + b1); h2 = out1 @ W2 (64x10); layer-2 alpha dots. thread/node
__global__ void k_fin1(const float* __restrict__ agg, const float* __restrict__ b1,
                       const float* __restrict__ W2,
                       const float* __restrict__ a_src2, const float* __restrict__ a_dst2,
                       float* __restrict__ h2, float* __restrict__ asrc2,
                       float* __restrict__ adst2, int N) {
    int n = blockIdx.x * 256 + threadIdx.x;
    if (n >= N) return;
    float acc[10];
#pragma unroll
    for (int j = 0; j < 10; ++j) acc[j] = 0.f;
    const float* ar = agg + (size_t)n * 64;
#pragma unroll 8
    for (int k = 0; k < 64; ++k) {
        float r = ar[k] + b1[k];
        r = r > 0.f ? r : expm1f(r);   // elu
#pragma unroll
        for (int j = 0; j < 10; ++j) acc[j] = fmaf(r, W2[k * 10 + j], acc[j]);
    }
    float s = 0.f, d = 0.f;
#pragma unroll
    for (int j = 0; j < 10; ++j) {
        h2[(size_t)n * 10 + j] = acc[j];
        s = fmaf(acc[j], a_src2[j], s);
        d = fmaf(acc[j], a_dst2[j], d);
    }
    asrc2[n] = s;
    adst2[n] = d;
}

// ---------------- layer 2 (heads=1, C=10) ----------------

__global__ void k_edge_max2(const int* __restrict__ src, const int* __restrict__ dst,
                            int E, int ET,
                            const float* __restrict__ asrc2, const float* __restrict__ adst2,
                            unsigned* __restrict__ m2) {
    int e = blockIdx.x * 256 + threadIdx.x;
    if (e >= ET) return;
    int s, d;
    if (e < E) { s = src[e]; d = dst[e]; } else { s = d = e - E; }
    float v = asrc2[s] + adst2[d];
    v = LRELU(v);
    atomicMax(&m2[d], f2ord(v));
}

__global__ void k_edge_sum2(const int* __restrict__ src, const int* __restrict__ dst,
                            int E, int ET,
                            const float* __restrict__ asrc2, const float* __restrict__ adst2,
                            const unsigned* __restrict__ m2, float* __restrict__ denom2) {
    int e = blockIdx.x * 256 + threadIdx.x;
    if (e >= ET) return;
    int s, d;
    if (e < E) { s = src[e]; d = dst[e]; } else { s = d = e - E; }
    float v = asrc2[s] + adst2[d];
    v = LRELU(v);
    atomicAdd(&denom2[d], __expf(v - ord2f(m2[d])));
}

__global__ void k_edge_agg2(const int* __restrict__ src, const int* __restrict__ dst,
                            int E, int ET,
                            const float* __restrict__ asrc2, const float* __restrict__ adst2,
                            const unsigned* __restrict__ m2, const float* __restrict__ denom2,
                            const float* __restrict__ h2, float* __restrict__ agg2) {
    int e = blockIdx.x * 256 + threadIdx.x;
    if (e >= ET) return;
    int s, d;
    if (e < E) { s = src[e]; d = dst[e]; } else { s = d = e - E; }
    float v = asrc2[s] + adst2[d];
    v = LRELU(v);
    float alpha = __expf(v - ord2f(m2[d])) / (denom2[d] + 1e-16f);
    const float* hr = h2 + (size_t)s * 10;
    float* ag = agg2 + (size_t)d * 10;
#pragma unroll
    for (int j = 0; j < 10; ++j) atomicAdd(&ag[j], hr[j] * alpha);
}

// pooled[g] += agg2[n] + b2 ; cnt[g] += 1
__global__ void k_pool(const float* __restrict__ agg2, const float* __restrict__ b2,
                       const int* __restrict__ batch, float* __restrict__ pooled,
                       float* __restrict__ cnt, int N) {
    int n = blockIdx.x * 256 + threadIdx.x;
    if (n >= N) return;
    int g = batch[n];
    const float* ar = agg2 + (size_t)n * 10;
    float* pg = pooled + (size_t)g * 10;
#pragma unroll
    for (int j = 0; j < 10; ++j) atomicAdd(&pg[j], ar[j] + b2[j]);
    atomicAdd(&cnt[g], 1.f);
}

// log_softmax over [G,10]; thread per graph
__global__ void k_final(const float* __restrict__ pooled, const float* __restrict__ cnt,
                        float* __restrict__ out, int G) {
    int t = blockIdx.x * 256 + threadIdx.x;
    if (t >= G) return;
    float c = fmaxf(cnt[t], 1.f);
    float v[10];
    float m = -1e30f;
#pragma unroll
    for (int j = 0; j < 10; ++j) {
        v[j] = pooled[(size_t)t * 10 + j] / c;
        m = fmaxf(m, v[j]);
    }
    float s = 0.f;
#pragma unroll
    for (int j = 0; j < 10; ++j) s += expf(v[j] - m);
    float ls = logf(s);
#pragma unroll
    for (int j = 0; j < 10; ++j) out[(size_t)t * 10 + j] = v[j] - m - ls;
}

extern "C" void kernel_launch(void* const* d_in, const int* in_sizes, int n_in,
                              void* d_out, int out_size, void* d_ws, size_t ws_size,
                              hipStream_t stream) {
    const float* x     = (const float*)d_in[0];
    const int*   ei    = (const int*)d_in[1];
    const int*   batch = (const int*)d_in[2];
    const float* W1    = (const float*)d_in[3];
    const float* as1w  = (const float*)d_in[4];
    const float* ad1w  = (const float*)d_in[5];
    const float* b1    = (const float*)d_in[6];
    const float* W2    = (const float*)d_in[7];
    const float* as2w  = (const float*)d_in[8];
    const float* ad2w  = (const float*)d_in[9];
    const float* b2    = (const float*)d_in[10];

    const int N  = in_sizes[0] / 128;
    const int E  = in_sizes[1] / 2;
    const int ET = E + N;              // + self loops
    const int G  = out_size / 10;
    const int* src = ei;
    const int* dst = ei + E;

    // ---- workspace layout (floats) ----
    size_t Nz = (size_t)N;
    float* h1     = (float*)d_ws;          // N*64
    float* asrc1  = h1 + Nz * 64;          // N*8
    float* adst1  = asrc1 + Nz * 8;        // N*8
    float* h2     = adst1 + Nz * 8;        // N*10
    float* asrc2  = h2 + Nz * 10;          // N
    float* adst2  = asrc2 + Nz;            // N
    // zero-initialized region (single memset):
    float* zstart = adst2 + Nz;
    unsigned* m1  = (unsigned*)zstart;     // N*8
    float* denom1 = (float*)(m1 + Nz * 8); // N*8
    float* agg1   = denom1 + Nz * 8;       // N*64
    unsigned* m2  = (unsigned*)(agg1 + Nz * 64); // N
    float* denom2 = (float*)(m2 + Nz);     // N
    float* agg2   = denom2 + Nz;           // N*10
    float* pooled = agg2 + Nz * 10;        // G*10
    float* cnt    = pooled + (size_t)G * 10; // G
    size_t zbytes = ((size_t)(8 + 8 + 64 + 1 + 1 + 10) * Nz + (size_t)11 * G) * sizeof(float);
    hipMemsetAsync(zstart, 0, zbytes, stream);

    const int B = 256;
    auto cdiv = [](long long a, long long b) { return (int)((a + b - 1) / b); };

    k_gemm1<<<cdiv((long long)N * 64, B), B, 0, stream>>>(x, W1, h1, N);
    k_alpha1<<<cdiv((long long)N * 8, B), B, 0, stream>>>(h1, as1w, ad1w, asrc1, adst1, N);

    k_edge_max1<<<cdiv((long long)ET * 8, B), B, 0, stream>>>(src, dst, E, ET, asrc1, adst1, m1);
    k_edge_sum1<<<cdiv((long long)ET * 8, B), B, 0, stream>>>(src, dst, E, ET, asrc1, adst1, m1, denom1);
    k_edge_agg1<<<cdiv((long long)ET * 64, B), B, 0, stream>>>(src, dst, E, ET, asrc1, adst1, m1, denom1, h1, agg1);

    k_fin1<<<cdiv(N, B), B, 0, stream>>>(agg1, b1, W2, as2w, ad2w, h2, asrc2, adst2, N);

    k_edge_max2<<<cdiv(ET, B), B, 0, stream>>>(src, dst, E, ET, asrc2, adst2, m2);
    k_edge_sum2<<<cdiv(ET, B), B, 0, stream>>>(src, dst, E, ET, asrc2, adst2, m2, denom2);
    k_edge_agg2<<<cdiv(ET, B), B, 0, stream>>>(src, dst, E, ET, asrc2, adst2, m2, denom2, h2, agg2);

    k_pool<<<cdiv(N, B), B, 0, stream>>>(agg2, b2, batch, pooled, cnt, N);
    k_final<<<cdiv(G, B), B, 0, stream>>>(pooled, cnt, (float*)d_out, G);
}

// Round 2
// 769.762 us; speedup vs baseline: 2.5178x; 2.5178x over previous
//
#include <hip/hip_runtime.h>
#include <math.h>

#define NEG_SLOPE 0.2f
#define LRELU(v) ((v) > 0.f ? (v) : NEG_SLOPE * (v))

// ---------------- dense per-node kernels ----------------

// h1[n][64] = x[n][128] @ W1[128][64]; thread per (n,col)
__global__ void k_gemm1(const float* __restrict__ x, const float* __restrict__ W,
                        float* __restrict__ h1, int N) {
    int t = blockIdx.x * 256 + threadIdx.x;
    if (t >= N * 64) return;
    int n = t >> 6, col = t & 63;
    const float* xr = x + (size_t)n * 128;
    float acc = 0.f;
#pragma unroll
    for (int k = 0; k < 128; ++k) acc = fmaf(xr[k], W[k * 64 + col], acc);
    h1[t] = acc;
}

// alpha_src[n][h], alpha_dst[n][h]; thread per (n,h)
__global__ void k_alpha1(const float* __restrict__ h1, const float* __restrict__ a_src,
                         const float* __restrict__ a_dst, float* __restrict__ asrc,
                         float* __restrict__ adst, int N) {
    int t = blockIdx.x * 256 + threadIdx.x;
    if (t >= N * 8) return;
    int n = t >> 3, h = t & 7;
    const float* hp = h1 + (size_t)n * 64 + h * 8;
    const float* as = a_src + h * 8;
    const float* ad = a_dst + h * 8;
    float s = 0.f, d = 0.f;
#pragma unroll
    for (int c = 0; c < 8; ++c) {
        float hv = hp[c];
        s = fmaf(hv, as[c], s);
        d = fmaf(hv, ad[c], d);
    }
    asrc[t] = s;
    adst[t] = d;
}

// ---------------- CSR build (counting sort by dst) ----------------

__global__ void k_hist(const int* __restrict__ dst, int E, int ET, int* __restrict__ cnt) {
    int e = blockIdx.x * 256 + threadIdx.x;
    if (e >= ET) return;
    int d = (e < E) ? dst[e] : e - E;   // tail = self loops (n,n)
    atomicAdd(&cnt[d], 1);
}

// block-level inclusive scan (1024/block) + block sums
__global__ void k_scan_blk(const int* __restrict__ cnt, int N,
                           int* __restrict__ incl, int* __restrict__ bsum) {
    __shared__ int buf[1024];
    int i = blockIdx.x * 1024 + threadIdx.x;
    int v = (i < N) ? cnt[i] : 0;
    buf[threadIdx.x] = v;
    __syncthreads();
    for (int off = 1; off < 1024; off <<= 1) {
        int t = (threadIdx.x >= off) ? buf[threadIdx.x - off] : 0;
        __syncthreads();
        buf[threadIdx.x] += t;
        __syncthreads();
    }
    if (i < N) incl[i] = buf[threadIdx.x];
    if (threadIdx.x == 1023) bsum[blockIdx.x] = buf[1023];
}

__global__ void k_scan_top(const int* __restrict__ bsum, int nb, int* __restrict__ boff) {
    if (threadIdx.x == 0) {
        int run = 0;
        for (int b = 0; b < nb; ++b) { boff[b] = run; run += bsum[b]; }
    }
}

__global__ void k_scan_add(const int* __restrict__ incl, const int* __restrict__ cnt,
                           const int* __restrict__ boff, int N,
                           int* __restrict__ excl, int* __restrict__ cursor) {
    int i = blockIdx.x * 256 + threadIdx.x;
    if (i >= N) return;
    int ex = incl[i] - cnt[i] + boff[i >> 10];
    excl[i] = ex;
    cursor[i] = ex;
}

__global__ void k_scatter(const int* __restrict__ src, const int* __restrict__ dst,
                          int E, int ET, int* __restrict__ cursor, int* __restrict__ srcs) {
    int e = blockIdx.x * 256 + threadIdx.x;
    if (e >= ET) return;
    int s, d;
    if (e < E) { s = src[e]; d = dst[e]; } else { s = d = e - E; }
    int pos = atomicAdd(&cursor[d], 1);
    srcs[pos] = s;
}

// ---------------- layer 1: one wave per node, online softmax + agg ----------------
// lane = channel c in [0,64); head h = c>>3. All softmax state is lane-local
// (uniform within each 8-lane head group) -> zero shuffles, zero atomics.
__global__ void k_gather1(const int* __restrict__ srcs, const int* __restrict__ excl,
                          const int* __restrict__ cnt,
                          const float* __restrict__ asrc1, const float* __restrict__ adst1,
                          const float* __restrict__ h1, float* __restrict__ agg, int N) {
    int wid = (int)((blockIdx.x * 256 + threadIdx.x) >> 6);
    if (wid >= N) return;
    int lane = threadIdx.x & 63;
    int h = lane >> 3;
    int beg = excl[wid], c_ = cnt[wid];
    float adh = adst1[wid * 8 + h];
    float m = -INFINITY, den = 0.f, acc = 0.f;
    for (int i = 0; i < c_; ++i) {
        int s = srcs[beg + i];
        float ev = asrc1[s * 8 + h] + adh;
        ev = LRELU(ev);
        float mn = fmaxf(m, ev);
        float sc = __expf(m - mn);      // exp(-inf)=0 on first iter
        float w  = __expf(ev - mn);
        den = den * sc + w;
        acc = acc * sc + w * h1[(size_t)s * 64 + lane];
        m = mn;
    }
    agg[(size_t)wid * 64 + lane] = acc / (den + 1e-16f);
}

// out1 = elu(agg + b1); h2 = out1 @ W2 (64x10); layer-2 alpha dots. thread/node
__global__ void k_fin1(const float* __restrict__ agg, const float* __restrict__ b1,
                       const float* __restrict__ W2,
                       const float* __restrict__ a_src2, const float* __restrict__ a_dst2,
                       float* __restrict__ h2, float* __restrict__ asrc2,
                       float* __restrict__ adst2, int N) {
    int n = blockIdx.x * 256 + threadIdx.x;
    if (n >= N) return;
    float acc[10];
#pragma unroll
    for (int j = 0; j < 10; ++j) acc[j] = 0.f;
    const float* ar = agg + (size_t)n * 64;
#pragma unroll 8
    for (int k = 0; k < 64; ++k) {
        float r = ar[k] + b1[k];
        r = r > 0.f ? r : expm1f(r);   // elu
#pragma unroll
        for (int j = 0; j < 10; ++j) acc[j] = fmaf(r, W2[k * 10 + j], acc[j]);
    }
    float s = 0.f, d = 0.f;
#pragma unroll
    for (int j = 0; j < 10; ++j) {
        h2[(size_t)n * 10 + j] = acc[j];
        s = fmaf(acc[j], a_src2[j], s);
        d = fmaf(acc[j], a_dst2[j], d);
    }
    asrc2[n] = s;
    adst2[n] = d;
}

// ---------------- layer 2: one wave per node (heads=1, C=10) ----------------
__global__ void k_gather2(const int* __restrict__ srcs, const int* __restrict__ excl,
                          const int* __restrict__ cnt,
                          const float* __restrict__ asrc2, const float* __restrict__ adst2,
                          const float* __restrict__ h2, float* __restrict__ agg2, int N) {
    int wid = (int)((blockIdx.x * 256 + threadIdx.x) >> 6);
    if (wid >= N) return;
    int lane = threadIdx.x & 63;
    int beg = excl[wid], c_ = cnt[wid];
    float adn = adst2[wid];
    float m = -INFINITY, den = 0.f, acc = 0.f;
    for (int i = 0; i < c_; ++i) {
        int s = srcs[beg + i];
        float ev = asrc2[s] + adn;
        ev = LRELU(ev);
        float mn = fmaxf(m, ev);
        float sc = __expf(m - mn);
        float w  = __expf(ev - mn);
        den = den * sc + w;
        float hv = (lane < 10) ? h2[(size_t)s * 10 + lane] : 0.f;
        acc = acc * sc + w * hv;
        m = mn;
    }
    if (lane < 10) agg2[(size_t)wid * 10 + lane] = acc / (den + 1e-16f);
}

// ---------------- pool (+bias) + log_softmax; block per graph ----------------
__global__ void k_pool_final(const float* __restrict__ agg2, const float* __restrict__ b2,
                             const int* __restrict__ batch, float* __restrict__ out,
                             int N, int G) {
    int g = blockIdx.x;
    int lo = 0, hi = N;                       // lower_bound(batch, g)
    while (lo < hi) { int mid = (lo + hi) >> 1; if (batch[mid] < g) lo = mid + 1; else hi = mid; }
    int s = lo;
    lo = s; hi = N;                           // lower_bound(batch, g+1)
    while (lo < hi) { int mid = (lo + hi) >> 1; if (batch[mid] < g + 1) lo = mid + 1; else hi = mid; }
    int e = lo;
    int tid = threadIdx.x;
    float acc[10];
#pragma unroll
    for (int j = 0; j < 10; ++j) acc[j] = 0.f;
    for (int n = s + tid; n < e; n += 256) {
        const float* r = agg2 + (size_t)n * 10;
#pragma unroll
        for (int j = 0; j < 10; ++j) acc[j] += r[j];
    }
    __shared__ float red[256 * 10];
#pragma unroll
    for (int j = 0; j < 10; ++j) red[tid * 10 + j] = acc[j];
    __syncthreads();
    for (int st = 128; st > 0; st >>= 1) {
        if (tid < st)
#pragma unroll
            for (int j = 0; j < 10; ++j) red[tid * 10 + j] += red[(tid + st) * 10 + j];
        __syncthreads();
    }
    if (tid == 0) {
        int c = e - s;
        float v[10], m = -1e30f;
#pragma unroll
        for (int j = 0; j < 10; ++j) {
            v[j] = (c > 0) ? red[j] / (float)c + b2[j] : 0.f;
            m = fmaxf(m, v[j]);
        }
        float ssum = 0.f;
#pragma unroll
        for (int j = 0; j < 10; ++j) ssum += expf(v[j] - m);
        float ls = logf(ssum);
#pragma unroll
        for (int j = 0; j < 10; ++j) out[(size_t)g * 10 + j] = v[j] - m - ls;
    }
}

extern "C" void kernel_launch(void* const* d_in, const int* in_sizes, int n_in,
                              void* d_out, int out_size, void* d_ws, size_t ws_size,
                              hipStream_t stream) {
    const float* x     = (const float*)d_in[0];
    const int*   ei    = (const int*)d_in[1];
    const int*   batch = (const int*)d_in[2];
    const float* W1    = (const float*)d_in[3];
    const float* as1w  = (const float*)d_in[4];
    const float* ad1w  = (const float*)d_in[5];
    const float* b1    = (const float*)d_in[6];
    const float* W2    = (const float*)d_in[7];
    const float* as2w  = (const float*)d_in[8];
    const float* ad2w  = (const float*)d_in[9];
    const float* b2    = (const float*)d_in[10];

    const int N  = in_sizes[0] / 128;
    const int E  = in_sizes[1] / 2;
    const int ET = E + N;                  // + self loops
    const int G  = out_size / 10;
    const int* srcE = ei;
    const int* dstE = ei + E;

    // ---- workspace layout ----
    size_t Nz = (size_t)N;
    float* h1    = (float*)d_ws;           // N*64
    float* agg2  = h1;                     // ALIAS: reused after h1 is dead (post k_fin1)
    float* asrc1 = h1 + Nz * 64;           // N*8
    float* adst1 = asrc1 + Nz * 8;         // N*8
    float* h2    = adst1 + Nz * 8;         // N*10
    float* asrc2 = h2 + Nz * 10;           // N
    float* adst2 = asrc2 + Nz;             // N
    float* agg1  = adst2 + Nz;             // N*64
    int* cntA    = (int*)(agg1 + Nz * 64); // N
    int* inclA   = cntA + Nz;              // N
    int* exclA   = inclA + Nz;             // N
    int* curA    = exclA + Nz;             // N
    int* bsumA   = curA + Nz;              // <=512
    int* boffA   = bsumA + 512;            // <=512
    int* srcsA   = boffA + 512;            // ET
    // total ~ (160*N + 1024 + ET)*4B  ~= 71 MB

    hipMemsetAsync(cntA, 0, Nz * sizeof(int), stream);

    const int B = 256;
    auto cdiv = [](long long a, long long b) { return (int)((a + b - 1) / b); };

    k_gemm1<<<cdiv((long long)N * 64, B), B, 0, stream>>>(x, W1, h1, N);
    k_alpha1<<<cdiv((long long)N * 8, B), B, 0, stream>>>(h1, as1w, ad1w, asrc1, adst1, N);

    // CSR build
    k_hist<<<cdiv(ET, B), B, 0, stream>>>(dstE, E, ET, cntA);
    int nb = cdiv(N, 1024);
    k_scan_blk<<<nb, 1024, 0, stream>>>(cntA, N, inclA, bsumA);
    k_scan_top<<<1, 64, 0, stream>>>(bsumA, nb, boffA);
    k_scan_add<<<cdiv(N, B), B, 0, stream>>>(inclA, cntA, boffA, N, exclA, curA);
    k_scatter<<<cdiv(ET, B), B, 0, stream>>>(srcE, dstE, E, ET, curA, srcsA);

    // layer 1
    k_gather1<<<cdiv(N, 4), B, 0, stream>>>(srcsA, exclA, cntA, asrc1, adst1, h1, agg1, N);
    k_fin1<<<cdiv(N, B), B, 0, stream>>>(agg1, b1, W2, as2w, ad2w, h2, asrc2, adst2, N);

    // layer 2 (h1 now dead; agg2 aliases it)
    k_gather2<<<cdiv(N, 4), B, 0, stream>>>(srcsA, exclA, cntA, asrc2, adst2, h2, agg2, N);

    // pool + log_softmax
    k_pool_final<<<G, B, 0, stream>>>(agg2, b2, batch, (float*)d_out, N, G);
}

// Round 3
// 638.519 us; speedup vs baseline: 3.0353x; 1.2055x over previous
//
#include <hip/hip_runtime.h>
#include <math.h>

#define NEG_SLOPE 0.2f
#define LRELU(v) ((v) > 0.f ? (v) : NEG_SLOPE * (v))

// ---------------- layer-1 GEMM + fused alpha dots ----------------
// h1[n][64] = x[n][128] @ W1[128][64]
// W1 staged in LDS (32 KB). Block = 256 threads -> 64 nodes.
// Thread (g,h): g = tid>>3 (node pair), h = tid&7 (head = 8-col group).
// Each thread computes 2 nodes x 8 cols, then the per-head a_src/a_dst dots
// are thread-local -> alpha1 kernel fused away.
__global__ __launch_bounds__(256) void k_gemm1(
        const float* __restrict__ x, const float* __restrict__ W,
        const float* __restrict__ a_src, const float* __restrict__ a_dst,
        float* __restrict__ h1, float* __restrict__ asrc, float* __restrict__ adst,
        int N) {
    __shared__ float Wl[128 * 64];
    int tid = threadIdx.x;
    { // cooperative W load: 2048 float4 / 256 threads = 8 each
        const float4* W4 = (const float4*)W;
        float4* Wl4 = (float4*)Wl;
#pragma unroll
        for (int i = 0; i < 8; ++i) Wl4[tid + 256 * i] = W4[tid + 256 * i];
    }
    __syncthreads();

    int g = tid >> 3, h = tid & 7;
    int n0 = blockIdx.x * 64 + g * 2;
    int n1 = n0 + 1;
    bool v0 = n0 < N, v1 = n1 < N;
    const float4* x4 = (const float4*)x;

    float acca[8], accb[8];
#pragma unroll
    for (int c = 0; c < 8; ++c) { acca[c] = 0.f; accb[c] = 0.f; }

    const float4 z4 = {0.f, 0.f, 0.f, 0.f};
#pragma unroll 4
    for (int kk = 0; kk < 32; ++kk) {
        float4 xa = v0 ? x4[(size_t)n0 * 32 + kk] : z4;
        float4 xb = v1 ? x4[(size_t)n1 * 32 + kk] : z4;
#pragma unroll
        for (int j = 0; j < 4; ++j) {
            int k = kk * 4 + j;
            const float* wr = &Wl[k * 64 + h * 8];
            float xav = ((const float*)&xa)[j];
            float xbv = ((const float*)&xb)[j];
#pragma unroll
            for (int c = 0; c < 8; ++c) {
                float wv = wr[c];
                acca[c] = fmaf(xav, wv, acca[c]);
                accb[c] = fmaf(xbv, wv, accb[c]);
            }
        }
    }

    const float* as = a_src + h * 8;
    const float* ad = a_dst + h * 8;
    if (v0) {
        float s = 0.f, d = 0.f;
        float* hp = h1 + (size_t)n0 * 64 + h * 8;
#pragma unroll
        for (int c = 0; c < 8; ++c) {
            hp[c] = acca[c];
            s = fmaf(acca[c], as[c], s);
            d = fmaf(acca[c], ad[c], d);
        }
        asrc[n0 * 8 + h] = s;
        adst[n0 * 8 + h] = d;
    }
    if (v1) {
        float s = 0.f, d = 0.f;
        float* hp = h1 + (size_t)n1 * 64 + h * 8;
#pragma unroll
        for (int c = 0; c < 8; ++c) {
            hp[c] = accb[c];
            s = fmaf(accb[c], as[c], s);
            d = fmaf(accb[c], ad[c], d);
        }
        asrc[n1 * 8 + h] = s;
        adst[n1 * 8 + h] = d;
    }
}

// ---------------- CSR build (counting sort by dst) ----------------

__global__ void k_hist(const int* __restrict__ dst, int E, int ET, int* __restrict__ cnt) {
    int e = blockIdx.x * 256 + threadIdx.x;
    if (e >= ET) return;
    int d = (e < E) ? dst[e] : e - E;   // tail = self loops (n,n)
    atomicAdd(&cnt[d], 1);
}

// block-level inclusive scan (1024/block) + block sums
__global__ void k_scan_blk(const int* __restrict__ cnt, int N,
                           int* __restrict__ incl, int* __restrict__ bsum) {
    __shared__ int buf[1024];
    int i = blockIdx.x * 1024 + threadIdx.x;
    int v = (i < N) ? cnt[i] : 0;
    buf[threadIdx.x] = v;
    __syncthreads();
    for (int off = 1; off < 1024; off <<= 1) {
        int t = (threadIdx.x >= off) ? buf[threadIdx.x - off] : 0;
        __syncthreads();
        buf[threadIdx.x] += t;
        __syncthreads();
    }
    if (i < N) incl[i] = buf[threadIdx.x];
    if (threadIdx.x == 1023) bsum[blockIdx.x] = buf[1023];
}

__global__ void k_scan_top(const int* __restrict__ bsum, int nb, int* __restrict__ boff) {
    if (threadIdx.x == 0) {
        int run = 0;
        for (int b = 0; b < nb; ++b) { boff[b] = run; run += bsum[b]; }
    }
}

__global__ void k_scan_add(const int* __restrict__ incl, const int* __restrict__ cnt,
                           const int* __restrict__ boff, int N,
                           int* __restrict__ excl, int* __restrict__ cursor) {
    int i = blockIdx.x * 256 + threadIdx.x;
    if (i >= N) return;
    int ex = incl[i] - cnt[i] + boff[i >> 10];
    excl[i] = ex;
    cursor[i] = ex;
}

__global__ void k_scatter(const int* __restrict__ src, const int* __restrict__ dst,
                          int E, int ET, int* __restrict__ cursor, int* __restrict__ srcs) {
    int e = blockIdx.x * 256 + threadIdx.x;
    if (e >= ET) return;
    int s, d;
    if (e < E) { s = src[e]; d = dst[e]; } else { s = d = e - E; }
    int pos = atomicAdd(&cursor[d], 1);
    srcs[pos] = s;
}

// ---------------- layer 1: one wave per node, online softmax + agg ----------------
__global__ void k_gather1(const int* __restrict__ srcs, const int* __restrict__ excl,
                          const int* __restrict__ cnt,
                          const float* __restrict__ asrc1, const float* __restrict__ adst1,
                          const float* __restrict__ h1, float* __restrict__ agg, int N) {
    int wid = (int)((blockIdx.x * 256 + threadIdx.x) >> 6);
    if (wid >= N) return;
    int lane = threadIdx.x & 63;
    int h = lane >> 3;
    int beg = excl[wid], c_ = cnt[wid];
    float adh = adst1[wid * 8 + h];
    float m = -INFINITY, den = 0.f, acc = 0.f;
    for (int i = 0; i < c_; ++i) {
        int s = srcs[beg + i];
        float ev = asrc1[s * 8 + h] + adh;
        ev = LRELU(ev);
        float mn = fmaxf(m, ev);
        float sc = __expf(m - mn);      // exp(-inf)=0 on first iter
        float w  = __expf(ev - mn);
        den = den * sc + w;
        acc = acc * sc + w * h1[(size_t)s * 64 + lane];
        m = mn;
    }
    agg[(size_t)wid * 64 + lane] = acc / (den + 1e-16f);
}

// out1 = elu(agg + b1); h2 = out1 @ W2 (64x10); layer-2 alpha dots. thread/node
__global__ void k_fin1(const float* __restrict__ agg, const float* __restrict__ b1,
                       const float* __restrict__ W2,
                       const float* __restrict__ a_src2, const float* __restrict__ a_dst2,
                       float* __restrict__ h2, float* __restrict__ asrc2,
                       float* __restrict__ adst2, int N) {
    int n = blockIdx.x * 256 + threadIdx.x;
    if (n >= N) return;
    float acc[10];
#pragma unroll
    for (int j = 0; j < 10; ++j) acc[j] = 0.f;
    const float* ar = agg + (size_t)n * 64;
#pragma unroll 8
    for (int k = 0; k < 64; ++k) {
        float r = ar[k] + b1[k];
        r = r > 0.f ? r : expm1f(r);   // elu
#pragma unroll
        for (int j = 0; j < 10; ++j) acc[j] = fmaf(r, W2[k * 10 + j], acc[j]);
    }
    float s = 0.f, d = 0.f;
#pragma unroll
    for (int j = 0; j < 10; ++j) {
        h2[(size_t)n * 10 + j] = acc[j];
        s = fmaf(acc[j], a_src2[j], s);
        d = fmaf(acc[j], a_dst2[j], d);
    }
    asrc2[n] = s;
    adst2[n] = d;
}

// ---------------- layer 2: one wave per node (heads=1, C=10) ----------------
__global__ void k_gather2(const int* __restrict__ srcs, const int* __restrict__ excl,
                          const int* __restrict__ cnt,
                          const float* __restrict__ asrc2, const float* __restrict__ adst2,
                          const float* __restrict__ h2, float* __restrict__ agg2, int N) {
    int wid = (int)((blockIdx.x * 256 + threadIdx.x) >> 6);
    if (wid >= N) return;
    int lane = threadIdx.x & 63;
    int beg = excl[wid], c_ = cnt[wid];
    float adn = adst2[wid];
    float m = -INFINITY, den = 0.f, acc = 0.f;
    for (int i = 0; i < c_; ++i) {
        int s = srcs[beg + i];
        float ev = asrc2[s] + adn;
        ev = LRELU(ev);
        float mn = fmaxf(m, ev);
        float sc = __expf(m - mn);
        float w  = __expf(ev - mn);
        den = den * sc + w;
        float hv = (lane < 10) ? h2[(size_t)s * 10 + lane] : 0.f;
        acc = acc * sc + w * hv;
        m = mn;
    }
    if (lane < 10) agg2[(size_t)wid * 10 + lane] = acc / (den + 1e-16f);
}

// ---------------- pool (+bias) + log_softmax; block per graph ----------------
__global__ void k_pool_final(const float* __restrict__ agg2, const float* __restrict__ b2,
                             const int* __restrict__ batch, float* __restrict__ out,
                             int N, int G) {
    int g = blockIdx.x;
    int lo = 0, hi = N;                       // lower_bound(batch, g)
    while (lo < hi) { int mid = (lo + hi) >> 1; if (batch[mid] < g) lo = mid + 1; else hi = mid; }
    int s = lo;
    lo = s; hi = N;                           // lower_bound(batch, g+1)
    while (lo < hi) { int mid = (lo + hi) >> 1; if (batch[mid] < g + 1) lo = mid + 1; else hi = mid; }
    int e = lo;
    int tid = threadIdx.x;
    float acc[10];
#pragma unroll
    for (int j = 0; j < 10; ++j) acc[j] = 0.f;
    for (int n = s + tid; n < e; n += 256) {
        const float* r = agg2 + (size_t)n * 10;
#pragma unroll
        for (int j = 0; j < 10; ++j) acc[j] += r[j];
    }
    __shared__ float red[256 * 10];
#pragma unroll
    for (int j = 0; j < 10; ++j) red[tid * 10 + j] = acc[j];
    __syncthreads();
    for (int st = 128; st > 0; st >>= 1) {
        if (tid < st)
#pragma unroll
            for (int j = 0; j < 10; ++j) red[tid * 10 + j] += red[(tid + st) * 10 + j];
        __syncthreads();
    }
    if (tid == 0) {
        int c = e - s;
        float v[10], m = -1e30f;
#pragma unroll
        for (int j = 0; j < 10; ++j) {
            v[j] = (c > 0) ? red[j] / (float)c + b2[j] : 0.f;
            m = fmaxf(m, v[j]);
        }
        float ssum = 0.f;
#pragma unroll
        for (int j = 0; j < 10; ++j) ssum += expf(v[j] - m);
        float ls = logf(ssum);
#pragma unroll
        for (int j = 0; j < 10; ++j) out[(size_t)g * 10 + j] = v[j] - m - ls;
    }
}

extern "C" void kernel_launch(void* const* d_in, const int* in_sizes, int n_in,
                              void* d_out, int out_size, void* d_ws, size_t ws_size,
                              hipStream_t stream) {
    const float* x     = (const float*)d_in[0];
    const int*   ei    = (const int*)d_in[1];
    const int*   batch = (const int*)d_in[2];
    const float* W1    = (const float*)d_in[3];
    const float* as1w  = (const float*)d_in[4];
    const float* ad1w  = (const float*)d_in[5];
    const float* b1    = (const float*)d_in[6];
    const float* W2    = (const float*)d_in[7];
    const float* as2w  = (const float*)d_in[8];
    const float* ad2w  = (const float*)d_in[9];
    const float* b2    = (const float*)d_in[10];

    const int N  = in_sizes[0] / 128;
    const int E  = in_sizes[1] / 2;
    const int ET = E + N;                  // + self loops
    const int G  = out_size / 10;
    const int* srcE = ei;
    const int* dstE = ei + E;

    // ---- workspace layout ----
    size_t Nz = (size_t)N;
    float* h1    = (float*)d_ws;           // N*64
    float* agg2  = h1;                     // ALIAS: reused after h1 is dead (post k_fin1)
    float* asrc1 = h1 + Nz * 64;           // N*8
    float* adst1 = asrc1 + Nz * 8;         // N*8
    float* h2    = adst1 + Nz * 8;         // N*10
    float* asrc2 = h2 + Nz * 10;           // N
    float* adst2 = asrc2 + Nz;             // N
    float* agg1  = adst2 + Nz;             // N*64
    int* cntA    = (int*)(agg1 + Nz * 64); // N
    int* inclA   = cntA + Nz;              // N
    int* exclA   = inclA + Nz;             // N
    int* curA    = exclA + Nz;             // N
    int* bsumA   = curA + Nz;              // <=512
    int* boffA   = bsumA + 512;            // <=512
    int* srcsA   = boffA + 512;            // ET

    hipMemsetAsync(cntA, 0, Nz * sizeof(int), stream);

    const int B = 256;
    auto cdiv = [](long long a, long long b) { return (int)((a + b - 1) / b); };

    // layer-1 GEMM with fused alpha dots (64 nodes/block)
    k_gemm1<<<cdiv(N, 64), B, 0, stream>>>(x, W1, as1w, ad1w, h1, asrc1, adst1, N);

    // CSR build
    k_hist<<<cdiv(ET, B), B, 0, stream>>>(dstE, E, ET, cntA);
    int nb = cdiv(N, 1024);
    k_scan_blk<<<nb, 1024, 0, stream>>>(cntA, N, inclA, bsumA);
    k_scan_top<<<1, 64, 0, stream>>>(bsumA, nb, boffA);
    k_scan_add<<<cdiv(N, B), B, 0, stream>>>(inclA, cntA, boffA, N, exclA, curA);
    k_scatter<<<cdiv(ET, B), B, 0, stream>>>(srcE, dstE, E, ET, curA, srcsA);

    // layer 1
    k_gather1<<<cdiv(N, 4), B, 0, stream>>>(srcsA, exclA, cntA, asrc1, adst1, h1, agg1, N);
    k_fin1<<<cdiv(N, B), B, 0, stream>>>(agg1, b1, W2, as2w, ad2w, h2, asrc2, adst2, N);

    // layer 2 (h1 now dead; agg2 aliases it)
    k_gather2<<<cdiv(N, 4), B, 0, stream>>>(srcsA, exclA, cntA, asrc2, adst2, h2, agg2, N);

    // pool + log_softmax
    k_pool_final<<<G, B, 0, stream>>>(agg2, b2, batch, (float*)d_out, N, G);
}

// Round 4
// 336.579 us; speedup vs baseline: 5.7583x; 1.8971x over previous
//
#include <hip/hip_runtime.h>
#include <math.h>

#define NEG_SLOPE 0.2f
#define LRELU(v) ((v) > 0.f ? (v) : NEG_SLOPE * (v))

// online-softmax chain update (lane-local)
#define UPD(mm, dd, aa, ev, hv)            \
    {                                      \
        float mn_ = fmaxf(mm, ev);         \
        float sc_ = __expf(mm - mn_);      \
        float w_  = __expf(ev - mn_);      \
        dd = dd * sc_ + w_;                \
        aa = aa * sc_ + w_ * (hv);         \
        mm = mn_;                          \
    }

// ---------------- layer-1 GEMM + fused alpha dots ----------------
__global__ __launch_bounds__(256) void k_gemm1(
        const float* __restrict__ x, const float* __restrict__ W,
        const float* __restrict__ a_src, const float* __restrict__ a_dst,
        float* __restrict__ h1, float* __restrict__ asrc, float* __restrict__ adst,
        int N) {
    __shared__ float Wl[128 * 64];
    int tid = threadIdx.x;
    {
        const float4* W4 = (const float4*)W;
        float4* Wl4 = (float4*)Wl;
#pragma unroll
        for (int i = 0; i < 8; ++i) Wl4[tid + 256 * i] = W4[tid + 256 * i];
    }
    __syncthreads();

    int g = tid >> 3, h = tid & 7;
    int n0 = blockIdx.x * 64 + g * 2;
    int n1 = n0 + 1;
    bool v0 = n0 < N, v1 = n1 < N;
    const float4* x4 = (const float4*)x;

    float acca[8], accb[8];
#pragma unroll
    for (int c = 0; c < 8; ++c) { acca[c] = 0.f; accb[c] = 0.f; }

    const float4 z4 = {0.f, 0.f, 0.f, 0.f};
#pragma unroll 4
    for (int kk = 0; kk < 32; ++kk) {
        float4 xa = v0 ? x4[(size_t)n0 * 32 + kk] : z4;
        float4 xb = v1 ? x4[(size_t)n1 * 32 + kk] : z4;
#pragma unroll
        for (int j = 0; j < 4; ++j) {
            int k = kk * 4 + j;
            const float* wr = &Wl[k * 64 + h * 8];
            float xav = ((const float*)&xa)[j];
            float xbv = ((const float*)&xb)[j];
#pragma unroll
            for (int c = 0; c < 8; ++c) {
                float wv = wr[c];
                acca[c] = fmaf(xav, wv, acca[c]);
                accb[c] = fmaf(xbv, wv, accb[c]);
            }
        }
    }

    const float* as = a_src + h * 8;
    const float* ad = a_dst + h * 8;
    if (v0) {
        float s = 0.f, d = 0.f;
        float* hp = h1 + (size_t)n0 * 64 + h * 8;
#pragma unroll
        for (int c = 0; c < 8; ++c) {
            hp[c] = acca[c];
            s = fmaf(acca[c], as[c], s);
            d = fmaf(acca[c], ad[c], d);
        }
        asrc[n0 * 8 + h] = s;
        adst[n0 * 8 + h] = d;
    }
    if (v1) {
        float s = 0.f, d = 0.f;
        float* hp = h1 + (size_t)n1 * 64 + h * 8;
#pragma unroll
        for (int c = 0; c < 8; ++c) {
            hp[c] = accb[c];
            s = fmaf(accb[c], as[c], s);
            d = fmaf(accb[c], ad[c], d);
        }
        asrc[n1 * 8 + h] = s;
        adst[n1 * 8 + h] = d;
    }
}

// ---------------- CSR build (counting sort by dst) ----------------

// hist + per-edge rank (old count). Degrees ~Poisson(16): uint8 is ample.
__global__ void k_hist(const int* __restrict__ dst, int E, int ET,
                       int* __restrict__ cnt, unsigned char* __restrict__ rank) {
    int e = blockIdx.x * 256 + threadIdx.x;
    if (e >= ET) return;
    int d = (e < E) ? dst[e] : e - E;   // tail = self loops (n,n)
    rank[e] = (unsigned char)atomicAdd(&cnt[d], 1);
}

// block-level inclusive scan (1024/block) + block sums
__global__ void k_scan_blk(const int* __restrict__ cnt, int N,
                           int* __restrict__ incl, int* __restrict__ bsum) {
    __shared__ int buf[1024];
    int i = blockIdx.x * 1024 + threadIdx.x;
    int v = (i < N) ? cnt[i] : 0;
    buf[threadIdx.x] = v;
    __syncthreads();
    for (int off = 1; off < 1024; off <<= 1) {
        int t = (threadIdx.x >= off) ? buf[threadIdx.x - off] : 0;
        __syncthreads();
        buf[threadIdx.x] += t;
        __syncthreads();
    }
    if (i < N) incl[i] = buf[threadIdx.x];
    if (threadIdx.x == 1023) bsum[blockIdx.x] = buf[1023];
}

// parallel exclusive scan of block sums (single 1024-thread block)
__global__ void k_scan_top(const int* __restrict__ bsum, int nb, int* __restrict__ boff) {
    __shared__ int buf[1024];
    int t = threadIdx.x;
    int v = (t < nb) ? bsum[t] : 0;
    buf[t] = v;
    __syncthreads();
    for (int off = 1; off < 1024; off <<= 1) {
        int u = (t >= off) ? buf[t - off] : 0;
        __syncthreads();
        buf[t] += u;
        __syncthreads();
    }
    if (t < nb) boff[t] = buf[t] - v;
}

__global__ void k_scan_add(const int* __restrict__ incl, const int* __restrict__ cnt,
                           const int* __restrict__ boff, int N, int* __restrict__ excl) {
    int i = blockIdx.x * 256 + threadIdx.x;
    if (i >= N) return;
    excl[i] = incl[i] - cnt[i] + boff[i >> 10];
}

// atomic-free scatter using precomputed ranks
__global__ void k_scatter(const int* __restrict__ src, const int* __restrict__ dst,
                          int E, int ET, const int* __restrict__ excl,
                          const unsigned char* __restrict__ rank, int* __restrict__ srcs) {
    int e = blockIdx.x * 256 + threadIdx.x;
    if (e >= ET) return;
    int s, d;
    if (e < E) { s = src[e]; d = dst[e]; } else { s = d = e - E; }
    srcs[excl[d] + (int)rank[e]] = s;
}

// ---------------- layer 1: one wave per node, 4-chain online softmax ----------------
__global__ void k_gather1(const int* __restrict__ srcs, const int* __restrict__ excl,
                          const int* __restrict__ cnt,
                          const float* __restrict__ asrc1, const float* __restrict__ adst1,
                          const float* __restrict__ h1, float* __restrict__ agg, int N) {
    int wid = (int)((blockIdx.x * 256 + threadIdx.x) >> 6);
    if (wid >= N) return;
    wid = __builtin_amdgcn_readfirstlane(wid);
    int lane = threadIdx.x & 63;
    int h = lane >> 3;
    int beg = __builtin_amdgcn_readfirstlane(excl[wid]);
    int c_  = __builtin_amdgcn_readfirstlane(cnt[wid]);
    const int* sp = srcs + beg;
    float adh = adst1[wid * 8 + h];

    float m0 = -INFINITY, d0 = 0.f, a0 = 0.f;
    float m1 = -INFINITY, d1 = 0.f, a1 = 0.f;
    float m2 = -INFINITY, d2 = 0.f, a2 = 0.f;
    float m3 = -INFINITY, d3 = 0.f, a3 = 0.f;

    int i = 0;
    for (; i + 4 <= c_; i += 4) {
        int s0 = sp[i], s1 = sp[i + 1], s2 = sp[i + 2], s3 = sp[i + 3];
        float e0 = LRELU(asrc1[s0 * 8 + h] + adh);
        float e1 = LRELU(asrc1[s1 * 8 + h] + adh);
        float e2 = LRELU(asrc1[s2 * 8 + h] + adh);
        float e3 = LRELU(asrc1[s3 * 8 + h] + adh);
        float g0 = h1[(size_t)s0 * 64 + lane];
        float g1 = h1[(size_t)s1 * 64 + lane];
        float g2 = h1[(size_t)s2 * 64 + lane];
        float g3 = h1[(size_t)s3 * 64 + lane];
        UPD(m0, d0, a0, e0, g0);
        UPD(m1, d1, a1, e1, g1);
        UPD(m2, d2, a2, e2, g2);
        UPD(m3, d3, a3, e3, g3);
    }
    for (; i < c_; ++i) {
        int s = sp[i];
        float ev = LRELU(asrc1[s * 8 + h] + adh);
        float gv = h1[(size_t)s * 64 + lane];
        UPD(m0, d0, a0, ev, gv);
    }
    // merge 4 chains (empty chains have m=-inf -> weight 0)
    float mM = fmaxf(fmaxf(m0, m1), fmaxf(m2, m3));
    float w0 = __expf(m0 - mM), w1 = __expf(m1 - mM);
    float w2 = __expf(m2 - mM), w3 = __expf(m3 - mM);
    float den = d0 * w0 + d1 * w1 + d2 * w2 + d3 * w3;
    float acc = a0 * w0 + a1 * w1 + a2 * w2 + a3 * w3;
    agg[(size_t)wid * 64 + lane] = acc / (den + 1e-16f);
}

// out1 = elu(agg + b1); h2 = out1 @ W2 (64x10); layer-2 alpha dots. thread/node
__global__ void k_fin1(const float* __restrict__ agg, const float* __restrict__ b1,
                       const float* __restrict__ W2,
                       const float* __restrict__ a_src2, const float* __restrict__ a_dst2,
                       float* __restrict__ h2, float* __restrict__ asrc2,
                       float* __restrict__ adst2, int N) {
    int n = blockIdx.x * 256 + threadIdx.x;
    if (n >= N) return;
    float acc[10];
#pragma unroll
    for (int j = 0; j < 10; ++j) acc[j] = 0.f;
    const float* ar = agg + (size_t)n * 64;
#pragma unroll 8
    for (int k = 0; k < 64; ++k) {
        float r = ar[k] + b1[k];
        r = r > 0.f ? r : expm1f(r);   // elu
#pragma unroll
        for (int j = 0; j < 10; ++j) acc[j] = fmaf(r, W2[k * 10 + j], acc[j]);
    }
    float s = 0.f, d = 0.f;
#pragma unroll
    for (int j = 0; j < 10; ++j) {
        h2[(size_t)n * 10 + j] = acc[j];
        s = fmaf(acc[j], a_src2[j], s);
        d = fmaf(acc[j], a_dst2[j], d);
    }
    asrc2[n] = s;
    adst2[n] = d;
}

// ---------------- layer 2: one wave per node, 4-chain (heads=1, C=10) ----------------
__global__ void k_gather2(const int* __restrict__ srcs, const int* __restrict__ excl,
                          const int* __restrict__ cnt,
                          const float* __restrict__ asrc2, const float* __restrict__ adst2,
                          const float* __restrict__ h2, float* __restrict__ agg2, int N) {
    int wid = (int)((blockIdx.x * 256 + threadIdx.x) >> 6);
    if (wid >= N) return;
    wid = __builtin_amdgcn_readfirstlane(wid);
    int lane = threadIdx.x & 63;
    int beg = __builtin_amdgcn_readfirstlane(excl[wid]);
    int c_  = __builtin_amdgcn_readfirstlane(cnt[wid]);
    const int* sp = srcs + beg;
    float adn = adst2[wid];
    bool ld = lane < 10;

    float m0 = -INFINITY, d0 = 0.f, a0 = 0.f;
    float m1 = -INFINITY, d1 = 0.f, a1 = 0.f;
    float m2 = -INFINITY, d2 = 0.f, a2 = 0.f;
    float m3 = -INFINITY, d3 = 0.f, a3 = 0.f;

    int i = 0;
    for (; i + 4 <= c_; i += 4) {
        int s0 = sp[i], s1 = sp[i + 1], s2 = sp[i + 2], s3 = sp[i + 3];
        float e0 = LRELU(asrc2[s0] + adn);
        float e1 = LRELU(asrc2[s1] + adn);
        float e2 = LRELU(asrc2[s2] + adn);
        float e3 = LRELU(asrc2[s3] + adn);
        float g0 = ld ? h2[(size_t)s0 * 10 + lane] : 0.f;
        float g1 = ld ? h2[(size_t)s1 * 10 + lane] : 0.f;
        float g2 = ld ? h2[(size_t)s2 * 10 + lane] : 0.f;
        float g3 = ld ? h2[(size_t)s3 * 10 + lane] : 0.f;
        UPD(m0, d0, a0, e0, g0);
        UPD(m1, d1, a1, e1, g1);
        UPD(m2, d2, a2, e2, g2);
        UPD(m3, d3, a3, e3, g3);
    }
    for (; i < c_; ++i) {
        int s = sp[i];
        float ev = LRELU(asrc2[s] + adn);
        float gv = ld ? h2[(size_t)s * 10 + lane] : 0.f;
        UPD(m0, d0, a0, ev, gv);
    }
    float mM = fmaxf(fmaxf(m0, m1), fmaxf(m2, m3));
    float w0 = __expf(m0 - mM), w1 = __expf(m1 - mM);
    float w2 = __expf(m2 - mM), w3 = __expf(m3 - mM);
    float den = d0 * w0 + d1 * w1 + d2 * w2 + d3 * w3;
    float acc = a0 * w0 + a1 * w1 + a2 * w2 + a3 * w3;
    if (ld) agg2[(size_t)wid * 10 + lane] = acc / (den + 1e-16f);
}

// ---------------- pool (+bias) + log_softmax; block per graph ----------------
__global__ void k_pool_final(const float* __restrict__ agg2, const float* __restrict__ b2,
                             const int* __restrict__ batch, float* __restrict__ out,
                             int N, int G) {
    int g = blockIdx.x;
    int lo = 0, hi = N;
    while (lo < hi) { int mid = (lo + hi) >> 1; if (batch[mid] < g) lo = mid + 1; else hi = mid; }
    int s = lo;
    lo = s; hi = N;
    while (lo < hi) { int mid = (lo + hi) >> 1; if (batch[mid] < g + 1) lo = mid + 1; else hi = mid; }
    int e = lo;
    int tid = threadIdx.x;
    float acc[10];
#pragma unroll
    for (int j = 0; j < 10; ++j) acc[j] = 0.f;
    for (int n = s + tid; n < e; n += 256) {
        const float* r = agg2 + (size_t)n * 10;
#pragma unroll
        for (int j = 0; j < 10; ++j) acc[j] += r[j];
    }
    __shared__ float red[256 * 10];
#pragma unroll
    for (int j = 0; j < 10; ++j) red[tid * 10 + j] = acc[j];
    __syncthreads();
    for (int st = 128; st > 0; st >>= 1) {
        if (tid < st)
#pragma unroll
            for (int j = 0; j < 10; ++j) red[tid * 10 + j] += red[(tid + st) * 10 + j];
        __syncthreads();
    }
    if (tid == 0) {
        int c = e - s;
        float v[10], m = -1e30f;
#pragma unroll
        for (int j = 0; j < 10; ++j) {
            v[j] = (c > 0) ? red[j] / (float)c + b2[j] : 0.f;
            m = fmaxf(m, v[j]);
        }
        float ssum = 0.f;
#pragma unroll
        for (int j = 0; j < 10; ++j) ssum += expf(v[j] - m);
        float ls = logf(ssum);
#pragma unroll
        for (int j = 0; j < 10; ++j) out[(size_t)g * 10 + j] = v[j] - m - ls;
    }
}

extern "C" void kernel_launch(void* const* d_in, const int* in_sizes, int n_in,
                              void* d_out, int out_size, void* d_ws, size_t ws_size,
                              hipStream_t stream) {
    const float* x     = (const float*)d_in[0];
    const int*   ei    = (const int*)d_in[1];
    const int*   batch = (const int*)d_in[2];
    const float* W1    = (const float*)d_in[3];
    const float* as1w  = (const float*)d_in[4];
    const float* ad1w  = (const float*)d_in[5];
    const float* b1    = (const float*)d_in[6];
    const float* W2    = (const float*)d_in[7];
    const float* as2w  = (const float*)d_in[8];
    const float* ad2w  = (const float*)d_in[9];
    const float* b2    = (const float*)d_in[10];

    const int N  = in_sizes[0] / 128;
    const int E  = in_sizes[1] / 2;
    const int ET = E + N;                  // + self loops
    const int G  = out_size / 10;
    const int* srcE = ei;
    const int* dstE = ei + E;

    // ---- workspace layout ----
    size_t Nz = (size_t)N;
    float* h1    = (float*)d_ws;           // N*64
    float* agg2  = h1;                     // ALIAS: reused after h1 dead (post k_fin1)
    float* asrc1 = h1 + Nz * 64;           // N*8
    float* adst1 = asrc1 + Nz * 8;         // N*8
    float* h2    = adst1 + Nz * 8;         // N*10
    float* asrc2 = h2 + Nz * 10;           // N
    float* adst2 = asrc2 + Nz;             // N
    float* agg1  = adst2 + Nz;             // N*64
    int* cntA    = (int*)(agg1 + Nz * 64); // N
    int* inclA   = cntA + Nz;              // N
    int* exclA   = inclA + Nz;             // N
    int* bsumA   = exclA + Nz;             // <=1024
    int* boffA   = bsumA + 1024;           // <=1024
    int* srcsA   = boffA + 1024;           // ET
    unsigned char* rankA = (unsigned char*)(srcsA + ET); // ET bytes

    hipMemsetAsync(cntA, 0, Nz * sizeof(int), stream);

    const int B = 256;
    auto cdiv = [](long long a, long long b) { return (int)((a + b - 1) / b); };

    // layer-1 GEMM with fused alpha dots (64 nodes/block)
    k_gemm1<<<cdiv(N, 64), B, 0, stream>>>(x, W1, as1w, ad1w, h1, asrc1, adst1, N);

    // CSR build
    k_hist<<<cdiv(ET, B), B, 0, stream>>>(dstE, E, ET, cntA, rankA);
    int nb = cdiv(N, 1024);
    k_scan_blk<<<nb, 1024, 0, stream>>>(cntA, N, inclA, bsumA);
    k_scan_top<<<1, 1024, 0, stream>>>(bsumA, nb, boffA);
    k_scan_add<<<cdiv(N, B), B, 0, stream>>>(inclA, cntA, boffA, N, exclA);
    k_scatter<<<cdiv(ET, B), B, 0, stream>>>(srcE, dstE, E, ET, exclA, rankA, srcsA);

    // layer 1
    k_gather1<<<cdiv(N, 4), B, 0, stream>>>(srcsA, exclA, cntA, asrc1, adst1, h1, agg1, N);
    k_fin1<<<cdiv(N, B), B, 0, stream>>>(agg1, b1, W2, as2w, ad2w, h2, asrc2, adst2, N);

    // layer 2 (h1 now dead; agg2 aliases it)
    k_gather2<<<cdiv(N, 4), B, 0, stream>>>(srcsA, exclA, cntA, asrc2, adst2, h2, agg2, N);

    // pool + log_softmax
    k_pool_final<<<G, B, 0, stream>>>(agg2, b2, batch, (float*)d_out, N, G);
}

// Round 6
// 291.618 us; speedup vs baseline: 6.6461x; 1.1542x over previous
//
#include <hip/hip_runtime.h>
#include <math.h>

#define L2E 1.44269504088896f
// LeakyReLU(v) == max(v, 0.2v) for all v (slope<1): 2 VALU ops
#define LRELU(v) fmaxf((v), 0.2f * (v))

// v_exp_f32 (2^x) without touching glibc's reserved __exp2f name
__device__ __forceinline__ float fexp2(float v) { return __builtin_amdgcn_exp2f(v); }

// base-2 online-softmax update, 2 channels per lane
#define UPD2(mm, dd, ax, ay, ev, gx, gy)   \
    {                                      \
        float mn_ = fmaxf(mm, ev);         \
        float sc_ = fexp2(mm - mn_);       \
        float w_  = fexp2(ev - mn_);       \
        dd = dd * sc_ + w_;                \
        ax = ax * sc_ + w_ * (gx);         \
        ay = ay * sc_ + w_ * (gy);         \
        mm = mn_;                          \
    }
// single-channel variant
#define UPD1(mm, dd, aa, ev, hv)           \
    {                                      \
        float mn_ = fmaxf(mm, ev);         \
        float sc_ = fexp2(mm - mn_);       \
        float w_  = fexp2(ev - mn_);       \
        dd = dd * sc_ + w_;                \
        aa = aa * sc_ + w_ * (hv);         \
        mm = mn_;                          \
    }

// ---------------- fat kernel: layer-1 GEMM (+alpha dots, x log2e) ∥ histogram ----------------
__global__ __launch_bounds__(256) void k_gemm1_hist(
        const float* __restrict__ x, const float* __restrict__ W,
        const float* __restrict__ a_src, const float* __restrict__ a_dst,
        float* __restrict__ h1, float* __restrict__ asrc, float* __restrict__ adst,
        const int* __restrict__ dstE, int* __restrict__ cnt, unsigned char* __restrict__ rank,
        int N, int E, int ET, int gemmBlocks) {
    if ((int)blockIdx.x >= gemmBlocks) {
        // ---- histogram part: per-edge rank via atomic ----
        int e = (blockIdx.x - gemmBlocks) * 256 + threadIdx.x;
        if (e < ET) {
            int d = (e < E) ? dstE[e] : e - E;   // tail = self loops
            rank[e] = (unsigned char)atomicAdd(&cnt[d], 1);
        }
        return;
    }
    // ---- GEMM part: 64 nodes per block ----
    __shared__ float Wl[128 * 64];
    int tid = threadIdx.x;
    {
        const float4* W4 = (const float4*)W;
        float4* Wl4 = (float4*)Wl;
#pragma unroll
        for (int i = 0; i < 8; ++i) Wl4[tid + 256 * i] = W4[tid + 256 * i];
    }
    __syncthreads();

    int g = tid >> 3, h = tid & 7;
    int n0 = blockIdx.x * 64 + g * 2;
    int n1 = n0 + 1;
    bool v0 = n0 < N, v1 = n1 < N;
    const float4* x4 = (const float4*)x;

    float acca[8], accb[8];
#pragma unroll
    for (int c = 0; c < 8; ++c) { acca[c] = 0.f; accb[c] = 0.f; }

    const float4 z4 = {0.f, 0.f, 0.f, 0.f};
#pragma unroll 4
    for (int kk = 0; kk < 32; ++kk) {
        float4 xa = v0 ? x4[(size_t)n0 * 32 + kk] : z4;
        float4 xb = v1 ? x4[(size_t)n1 * 32 + kk] : z4;
#pragma unroll
        for (int j = 0; j < 4; ++j) {
            int k = kk * 4 + j;
            const float* wr = &Wl[k * 64 + h * 8];
            float xav = ((const float*)&xa)[j];
            float xbv = ((const float*)&xb)[j];
#pragma unroll
            for (int c = 0; c < 8; ++c) {
                float wv = wr[c];
                acca[c] = fmaf(xav, wv, acca[c]);
                accb[c] = fmaf(xbv, wv, accb[c]);
            }
        }
    }

    const float* as = a_src + h * 8;
    const float* ad = a_dst + h * 8;
    if (v0) {
        float s = 0.f, d = 0.f;
        float* hp = h1 + (size_t)n0 * 64 + h * 8;
#pragma unroll
        for (int c = 0; c < 8; ++c) {
            hp[c] = acca[c];
            s = fmaf(acca[c], as[c], s);
            d = fmaf(acca[c], ad[c], d);
        }
        asrc[n0 * 8 + h] = s * L2E;   // base-2 domain for exp2 softmax
        adst[n0 * 8 + h] = d * L2E;
    }
    if (v1) {
        float s = 0.f, d = 0.f;
        float* hp = h1 + (size_t)n1 * 64 + h * 8;
#pragma unroll
        for (int c = 0; c < 8; ++c) {
            hp[c] = accb[c];
            s = fmaf(accb[c], as[c], s);
            d = fmaf(accb[c], ad[c], d);
        }
        asrc[n1 * 8 + h] = s * L2E;
        adst[n1 * 8 + h] = d * L2E;
    }
}

// ---------------- CSR scan + scatter ----------------

__global__ void k_scan_blk(const int* __restrict__ cnt, int N,
                           int* __restrict__ incl, int* __restrict__ bsum) {
    __shared__ int buf[1024];
    int i = blockIdx.x * 1024 + threadIdx.x;
    int v = (i < N) ? cnt[i] : 0;
    buf[threadIdx.x] = v;
    __syncthreads();
    for (int off = 1; off < 1024; off <<= 1) {
        int t = (threadIdx.x >= off) ? buf[threadIdx.x - off] : 0;
        __syncthreads();
        buf[threadIdx.x] += t;
        __syncthreads();
    }
    if (i < N) incl[i] = buf[threadIdx.x];
    if (threadIdx.x == 1023) bsum[blockIdx.x] = buf[1023];
}

__global__ void k_scan_top(const int* __restrict__ bsum, int nb, int* __restrict__ boff) {
    __shared__ int buf[1024];
    int t = threadIdx.x;
    int v = (t < nb) ? bsum[t] : 0;
    buf[t] = v;
    __syncthreads();
    for (int off = 1; off < 1024; off <<= 1) {
        int u = (t >= off) ? buf[t - off] : 0;
        __syncthreads();
        buf[t] += u;
        __syncthreads();
    }
    if (t < nb) boff[t] = buf[t] - v;
}

__global__ void k_scan_add(const int* __restrict__ incl, const int* __restrict__ cnt,
                           const int* __restrict__ boff, int N, int* __restrict__ excl) {
    int i = blockIdx.x * 256 + threadIdx.x;
    if (i >= N) return;
    excl[i] = incl[i] - cnt[i] + boff[i >> 10];
}

__global__ void k_scatter(const int* __restrict__ src, const int* __restrict__ dst,
                          int E, int ET, const int* __restrict__ excl,
                          const unsigned char* __restrict__ rank, int* __restrict__ srcs) {
    int e = blockIdx.x * 256 + threadIdx.x;
    if (e >= ET) return;
    int s, d;
    if (e < E) { s = src[e]; d = dst[e]; } else { s = d = e - E; }
    srcs[excl[d] + (int)rank[e]] = s;
}

// ---------------- layer 1 gather: 2 nodes/wave, 32 lanes/node, float2/lane ----------------
__global__ void k_gather1(const int* __restrict__ srcs, const int* __restrict__ excl,
                          const int* __restrict__ cnt,
                          const float* __restrict__ asrc1, const float* __restrict__ adst1,
                          const float* __restrict__ h1, float* __restrict__ agg, int N) {
    int tid = blockIdx.x * 256 + threadIdx.x;
    int wave = tid >> 6;
    int lane = threadIdx.x & 63;
    int half = lane >> 5;
    int l = lane & 31;            // lane within half-wave
    int wid = wave * 2 + half;    // node
    if (wid >= N) return;
    int h = l >> 2;               // head of channel pair
    int c0 = l * 2;               // channels c0, c0+1

    int beg = excl[wid];
    int cw  = cnt[wid];
    const int* sp = srcs + beg;
    float adh = adst1[wid * 8 + h];

    float m0 = -INFINITY, d0 = 0.f, ax0 = 0.f, ay0 = 0.f;
    float m1 = -INFINITY, d1 = 0.f, ax1 = 0.f, ay1 = 0.f;
    float m2 = -INFINITY, d2 = 0.f, ax2 = 0.f, ay2 = 0.f;
    float m3 = -INFINITY, d3 = 0.f, ax3 = 0.f, ay3 = 0.f;

    int i = 0;
    for (; i + 4 <= cw; i += 4) {
        int s0 = sp[i], s1 = sp[i + 1], s2 = sp[i + 2], s3 = sp[i + 3];
        float e0 = LRELU(asrc1[s0 * 8 + h] + adh);
        float e1 = LRELU(asrc1[s1 * 8 + h] + adh);
        float e2 = LRELU(asrc1[s2 * 8 + h] + adh);
        float e3 = LRELU(asrc1[s3 * 8 + h] + adh);
        float2 g0 = *(const float2*)&h1[(size_t)s0 * 64 + c0];
        float2 g1 = *(const float2*)&h1[(size_t)s1 * 64 + c0];
        float2 g2 = *(const float2*)&h1[(size_t)s2 * 64 + c0];
        float2 g3 = *(const float2*)&h1[(size_t)s3 * 64 + c0];
        UPD2(m0, d0, ax0, ay0, e0, g0.x, g0.y);
        UPD2(m1, d1, ax1, ay1, e1, g1.x, g1.y);
        UPD2(m2, d2, ax2, ay2, e2, g2.x, g2.y);
        UPD2(m3, d3, ax3, ay3, e3, g3.x, g3.y);
    }
    for (; i < cw; ++i) {
        int s = sp[i];
        float ev = LRELU(asrc1[s * 8 + h] + adh);
        float2 gv = *(const float2*)&h1[(size_t)s * 64 + c0];
        UPD2(m0, d0, ax0, ay0, ev, gv.x, gv.y);
    }
    float mM = fmaxf(fmaxf(m0, m1), fmaxf(m2, m3));
    float w0 = fexp2(m0 - mM), w1 = fexp2(m1 - mM);
    float w2 = fexp2(m2 - mM), w3 = fexp2(m3 - mM);
    float den = d0 * w0 + d1 * w1 + d2 * w2 + d3 * w3;
    float inv = 1.f / (den + 1e-16f);
    float2 r;
    r.x = (ax0 * w0 + ax1 * w1 + ax2 * w2 + ax3 * w3) * inv;
    r.y = (ay0 * w0 + ay1 * w1 + ay2 * w2 + ay3 * w3) * inv;
    *(float2*)&agg[(size_t)wid * 64 + c0] = r;
}

// out1 = elu(agg + b1); h2 = out1 @ W2 (64x10); layer-2 alpha dots (x log2e). thread/node
__global__ void k_fin1(const float* __restrict__ agg, const float* __restrict__ b1,
                       const float* __restrict__ W2,
                       const float* __restrict__ a_src2, const float* __restrict__ a_dst2,
                       float* __restrict__ h2, float* __restrict__ asrc2,
                       float* __restrict__ adst2, int N) {
    int n = blockIdx.x * 256 + threadIdx.x;
    if (n >= N) return;
    float acc[10];
#pragma unroll
    for (int j = 0; j < 10; ++j) acc[j] = 0.f;
    const float* ar = agg + (size_t)n * 64;
#pragma unroll 8
    for (int k = 0; k < 64; ++k) {
        float r = ar[k] + b1[k];
        r = r > 0.f ? r : expm1f(r);   // elu
#pragma unroll
        for (int j = 0; j < 10; ++j) acc[j] = fmaf(r, W2[k * 10 + j], acc[j]);
    }
    float s = 0.f, d = 0.f;
#pragma unroll
    for (int j = 0; j < 10; ++j) {
        h2[(size_t)n * 10 + j] = acc[j];
        s = fmaf(acc[j], a_src2[j], s);
        d = fmaf(acc[j], a_dst2[j], d);
    }
    asrc2[n] = s * L2E;
    adst2[n] = d * L2E;
}

// ---------------- layer 2 gather: 4 nodes/wave, 16 lanes/node ----------------
__global__ void k_gather2(const int* __restrict__ srcs, const int* __restrict__ excl,
                          const int* __restrict__ cnt,
                          const float* __restrict__ asrc2, const float* __restrict__ adst2,
                          const float* __restrict__ h2, float* __restrict__ agg2, int N) {
    int tid = blockIdx.x * 256 + threadIdx.x;
    int wave = tid >> 6;
    int lane = threadIdx.x & 63;
    int q = lane >> 4;            // node slot in wave
    int l = lane & 15;
    int wid = wave * 4 + q;
    if (wid >= N) return;

    int beg = excl[wid];
    int cw  = cnt[wid];
    const int* sp = srcs + beg;
    float adn = adst2[wid];
    bool ld = l < 10;

    float m0 = -INFINITY, d0 = 0.f, a0 = 0.f;
    float m1 = -INFINITY, d1 = 0.f, a1 = 0.f;
    float m2 = -INFINITY, d2 = 0.f, a2 = 0.f;
    float m3 = -INFINITY, d3 = 0.f, a3 = 0.f;

    int i = 0;
    for (; i + 4 <= cw; i += 4) {
        int s0 = sp[i], s1 = sp[i + 1], s2 = sp[i + 2], s3 = sp[i + 3];
        float e0 = LRELU(asrc2[s0] + adn);
        float e1 = LRELU(asrc2[s1] + adn);
        float e2 = LRELU(asrc2[s2] + adn);
        float e3 = LRELU(asrc2[s3] + adn);
        float g0 = ld ? h2[(size_t)s0 * 10 + l] : 0.f;
        float g1 = ld ? h2[(size_t)s1 * 10 + l] : 0.f;
        float g2 = ld ? h2[(size_t)s2 * 10 + l] : 0.f;
        float g3 = ld ? h2[(size_t)s3 * 10 + l] : 0.f;
        UPD1(m0, d0, a0, e0, g0);
        UPD1(m1, d1, a1, e1, g1);
        UPD1(m2, d2, a2, e2, g2);
        UPD1(m3, d3, a3, e3, g3);
    }
    for (; i < cw; ++i) {
        int s = sp[i];
        float ev = LRELU(asrc2[s] + adn);
        float gv = ld ? h2[(size_t)s * 10 + l] : 0.f;
        UPD1(m0, d0, a0, ev, gv);
    }
    float mM = fmaxf(fmaxf(m0, m1), fmaxf(m2, m3));
    float w0 = fexp2(m0 - mM), w1 = fexp2(m1 - mM);
    float w2 = fexp2(m2 - mM), w3 = fexp2(m3 - mM);
    float den = d0 * w0 + d1 * w1 + d2 * w2 + d3 * w3;
    float acc = a0 * w0 + a1 * w1 + a2 * w2 + a3 * w3;
    if (ld) agg2[(size_t)wid * 10 + l] = acc / (den + 1e-16f);
}

// ---------------- pool (+bias) + log_softmax; block per graph ----------------
__global__ void k_pool_final(const float* __restrict__ agg2, const float* __restrict__ b2,
                             const int* __restrict__ batch, float* __restrict__ out,
                             int N, int G) {
    int g = blockIdx.x;
    int lo = 0, hi = N;
    while (lo < hi) { int mid = (lo + hi) >> 1; if (batch[mid] < g) lo = mid + 1; else hi = mid; }
    int s = lo;
    lo = s; hi = N;
    while (lo < hi) { int mid = (lo + hi) >> 1; if (batch[mid] < g + 1) lo = mid + 1; else hi = mid; }
    int e = lo;
    int tid = threadIdx.x;
    float acc[10];
#pragma unroll
    for (int j = 0; j < 10; ++j) acc[j] = 0.f;
    for (int n = s + tid; n < e; n += 256) {
        const float* r = agg2 + (size_t)n * 10;
#pragma unroll
        for (int j = 0; j < 10; ++j) acc[j] += r[j];
    }
    __shared__ float red[256 * 10];
#pragma unroll
    for (int j = 0; j < 10; ++j) red[tid * 10 + j] = acc[j];
    __syncthreads();
    for (int st = 128; st > 0; st >>= 1) {
        if (tid < st)
#pragma unroll
            for (int j = 0; j < 10; ++j) red[tid * 10 + j] += red[(tid + st) * 10 + j];
        __syncthreads();
    }
    if (tid == 0) {
        int c = e - s;
        float v[10], m = -1e30f;
#pragma unroll
        for (int j = 0; j < 10; ++j) {
            v[j] = (c > 0) ? red[j] / (float)c + b2[j] : 0.f;
            m = fmaxf(m, v[j]);
        }
        float ssum = 0.f;
#pragma unroll
        for (int j = 0; j < 10; ++j) ssum += expf(v[j] - m);
        float ls = logf(ssum);
#pragma unroll
        for (int j = 0; j < 10; ++j) out[(size_t)g * 10 + j] = v[j] - m - ls;
    }
}

extern "C" void kernel_launch(void* const* d_in, const int* in_sizes, int n_in,
                              void* d_out, int out_size, void* d_ws, size_t ws_size,
                              hipStream_t stream) {
    const float* x     = (const float*)d_in[0];
    const int*   ei    = (const int*)d_in[1];
    const int*   batch = (const int*)d_in[2];
    const float* W1    = (const float*)d_in[3];
    const float* as1w  = (const float*)d_in[4];
    const float* ad1w  = (const float*)d_in[5];
    const float* b1    = (const float*)d_in[6];
    const float* W2    = (const float*)d_in[7];
    const float* as2w  = (const float*)d_in[8];
    const float* ad2w  = (const float*)d_in[9];
    const float* b2    = (const float*)d_in[10];

    const int N  = in_sizes[0] / 128;
    const int E  = in_sizes[1] / 2;
    const int ET = E + N;                  // + self loops
    const int G  = out_size / 10;
    const int* srcE = ei;
    const int* dstE = ei + E;

    // ---- workspace layout ----
    size_t Nz = (size_t)N;
    float* h1    = (float*)d_ws;           // N*64
    float* agg2  = h1;                     // ALIAS: reused after h1 dead (post k_fin1)
    float* asrc1 = h1 + Nz * 64;           // N*8
    float* adst1 = asrc1 + Nz * 8;         // N*8
    float* h2    = adst1 + Nz * 8;         // N*10
    float* asrc2 = h2 + Nz * 10;           // N
    float* adst2 = asrc2 + Nz;             // N
    float* agg1  = adst2 + Nz;             // N*64
    int* cntA    = (int*)(agg1 + Nz * 64); // N
    int* inclA   = cntA + Nz;              // N
    int* exclA   = inclA + Nz;             // N
    int* bsumA   = exclA + Nz;             // <=1024
    int* boffA   = bsumA + 1024;           // <=1024
    int* srcsA   = boffA + 1024;           // ET
    unsigned char* rankA = (unsigned char*)(srcsA + ET); // ET bytes

    hipMemsetAsync(cntA, 0, Nz * sizeof(int), stream);

    const int B = 256;
    auto cdiv = [](long long a, long long b) { return (int)((a + b - 1) / b); };

    // fused layer-1 GEMM + histogram
    int gemmBlocks = cdiv(N, 64);
    int histBlocks = cdiv(ET, B);
    k_gemm1_hist<<<gemmBlocks + histBlocks, B, 0, stream>>>(
        x, W1, as1w, ad1w, h1, asrc1, adst1, dstE, cntA, rankA, N, E, ET, gemmBlocks);

    // CSR scan + scatter
    int nb = cdiv(N, 1024);
    k_scan_blk<<<nb, 1024, 0, stream>>>(cntA, N, inclA, bsumA);
    k_scan_top<<<1, 1024, 0, stream>>>(bsumA, nb, boffA);
    k_scan_add<<<cdiv(N, B), B, 0, stream>>>(inclA, cntA, boffA, N, exclA);
    k_scatter<<<cdiv(ET, B), B, 0, stream>>>(srcE, dstE, E, ET, exclA, rankA, srcsA);

    // layer 1: 8 nodes per 256-thread block (2 per wave)
    k_gather1<<<cdiv(N, 8), B, 0, stream>>>(srcsA, exclA, cntA, asrc1, adst1, h1, agg1, N);
    k_fin1<<<cdiv(N, B), B, 0, stream>>>(agg1, b1, W2, as2w, ad2w, h2, asrc2, adst2, N);

    // layer 2: 16 nodes per block (4 per wave); agg2 aliases dead h1
    k_gather2<<<cdiv(N, 16), B, 0, stream>>>(srcsA, exclA, cntA, asrc2, adst2, h2, agg2, N);

    // pool + log_softmax
    k_pool_final<<<G, B, 0, stream>>>(agg2, b2, batch, (float*)d_out, N, G);
}

// Round 7
// 254.666 us; speedup vs baseline: 7.6105x; 1.1451x over previous
//
#include <hip/hip_runtime.h>
#include <math.h>

#define L2E 1.44269504088896f
#define LRELU(v) fmaxf((v), 0.2f * (v))

__device__ __forceinline__ float fexp2(float v) { return __builtin_amdgcn_exp2f(v); }

// base-2 online-softmax update, 2 channels per lane
#define UPD2(mm, dd, ax, ay, ev, gx, gy)   \
    {                                      \
        float mn_ = fmaxf(mm, ev);         \
        float sc_ = fexp2(mm - mn_);       \
        float w_  = fexp2(ev - mn_);       \
        dd = dd * sc_ + w_;                \
        ax = ax * sc_ + w_ * (gx);         \
        ay = ay * sc_ + w_ * (gy);         \
        mm = mn_;                          \
    }
#define UPD1(mm, dd, aa, ev, hv)           \
    {                                      \
        float mn_ = fmaxf(mm, ev);         \
        float sc_ = fexp2(mm - mn_);       \
        float w_  = fexp2(ev - mn_);       \
        dd = dd * sc_ + w_;                \
        aa = aa * sc_ + w_ * (hv);         \
        mm = mn_;                          \
    }

#define CH 4096   // edges per bucket-build block

// ---------------- layer-1 GEMM + fused alpha dots (x log2e) ----------------
__global__ __launch_bounds__(256) void k_gemm1(
        const float* __restrict__ x, const float* __restrict__ W,
        const float* __restrict__ a_src, const float* __restrict__ a_dst,
        float* __restrict__ h1, float* __restrict__ asrc, float* __restrict__ adst,
        int N) {
    __shared__ float Wl[128 * 64];
    int tid = threadIdx.x;
    {
        const float4* W4 = (const float4*)W;
        float4* Wl4 = (float4*)Wl;
#pragma unroll
        for (int i = 0; i < 8; ++i) Wl4[tid + 256 * i] = W4[tid + 256 * i];
    }
    __syncthreads();

    int g = tid >> 3, h = tid & 7;
    int n0 = blockIdx.x * 64 + g * 2;
    int n1 = n0 + 1;
    bool v0 = n0 < N, v1 = n1 < N;
    const float4* x4 = (const float4*)x;

    float acca[8], accb[8];
#pragma unroll
    for (int c = 0; c < 8; ++c) { acca[c] = 0.f; accb[c] = 0.f; }

    const float4 z4 = {0.f, 0.f, 0.f, 0.f};
#pragma unroll 4
    for (int kk = 0; kk < 32; ++kk) {
        float4 xa = v0 ? x4[(size_t)n0 * 32 + kk] : z4;
        float4 xb = v1 ? x4[(size_t)n1 * 32 + kk] : z4;
#pragma unroll
        for (int j = 0; j < 4; ++j) {
            int k = kk * 4 + j;
            const float* wr = &Wl[k * 64 + h * 8];
            float xav = ((const float*)&xa)[j];
            float xbv = ((const float*)&xb)[j];
#pragma unroll
            for (int c = 0; c < 8; ++c) {
                float wv = wr[c];
                acca[c] = fmaf(xav, wv, acca[c]);
                accb[c] = fmaf(xbv, wv, accb[c]);
            }
        }
    }

    const float* as = a_src + h * 8;
    const float* ad = a_dst + h * 8;
    if (v0) {
        float s = 0.f, d = 0.f;
        float* hp = h1 + (size_t)n0 * 64 + h * 8;
#pragma unroll
        for (int c = 0; c < 8; ++c) {
            hp[c] = acca[c];
            s = fmaf(acca[c], as[c], s);
            d = fmaf(acca[c], ad[c], d);
        }
        asrc[n0 * 8 + h] = s * L2E;
        adst[n0 * 8 + h] = d * L2E;
    }
    if (v1) {
        float s = 0.f, d = 0.f;
        float* hp = h1 + (size_t)n1 * 64 + h * 8;
#pragma unroll
        for (int c = 0; c < 8; ++c) {
            hp[c] = accb[c];
            s = fmaf(accb[c], as[c], s);
            d = fmaf(accb[c], ad[c], d);
        }
        asrc[n1 * 8 + h] = s * L2E;
        adst[n1 * 8 + h] = d * L2E;
    }
}

// ---------------- graph-bucket sort (zero global atomics) ----------------

// per-block LDS hist over 512 graph bins; bh[bin*NB + b]
__global__ __launch_bounds__(256) void k_bhist(const int* __restrict__ dstE,
                                               const int* __restrict__ batch,
                                               int E, int NB, int G, int* __restrict__ bh) {
    __shared__ int lh[512];
    int tid = threadIdx.x, b = blockIdx.x;
    lh[tid] = 0; lh[tid + 256] = 0;
    __syncthreads();
#pragma unroll
    for (int i = 0; i < CH / 256; ++i) {
        int e = b * CH + i * 256 + tid;
        if (e < E) atomicAdd(&lh[batch[dstE[e]]], 1);
    }
    __syncthreads();
    if (tid < G)       bh[(size_t)tid * NB + b] = lh[tid];
    if (tid + 256 < G) bh[(size_t)(tid + 256) * NB + b] = lh[tid + 256];
}

// per-bin exclusive scan across blocks: pstart[bin*NB+b], total[bin]. 512-thread block per bin.
__global__ __launch_bounds__(512) void k_mscan(const int* __restrict__ bh, int NB,
                                               int* __restrict__ pstart, int* __restrict__ total) {
    __shared__ int buf[512];
    int bin = blockIdx.x, t = threadIdx.x;
    int v = (t < NB) ? bh[(size_t)bin * NB + t] : 0;
    buf[t] = v;
    __syncthreads();
    for (int off = 1; off < 512; off <<= 1) {
        int u = (t >= off) ? buf[t - off] : 0;
        __syncthreads();
        buf[t] += u;
        __syncthreads();
    }
    if (t < NB) pstart[(size_t)bin * NB + t] = buf[t] - v;
    if (t == 511) total[bin] = buf[511];
}

// exclusive scan of per-bin totals -> boff
__global__ __launch_bounds__(1024) void k_scan_top(const int* __restrict__ total, int nb,
                                                   int* __restrict__ boff) {
    __shared__ int buf[1024];
    int t = threadIdx.x;
    int v = (t < nb) ? total[t] : 0;
    buf[t] = v;
    __syncthreads();
    for (int off = 1; off < 1024; off <<= 1) {
        int u = (t >= off) ? buf[t - off] : 0;
        __syncthreads();
        buf[t] += u;
        __syncthreads();
    }
    if (t < nb) boff[t] = buf[t] - v;
}

// scatter edges into graph buckets; LDS cursors only
__global__ __launch_bounds__(256) void k_bscatter(const int* __restrict__ srcE,
                                                  const int* __restrict__ dstE,
                                                  const int* __restrict__ batch,
                                                  const int* __restrict__ boff,
                                                  const int* __restrict__ pstart,
                                                  int E, int NB, int G, int2* __restrict__ pairs) {
    __shared__ int lstart[512];
    __shared__ int lc[512];
    int tid = threadIdx.x, b = blockIdx.x;
#pragma unroll
    for (int j = tid; j < 512; j += 256) {
        lstart[j] = (j < G) ? boff[j] + pstart[(size_t)j * NB + b] : 0;
        lc[j] = 0;
    }
    __syncthreads();
#pragma unroll
    for (int i = 0; i < CH / 256; ++i) {
        int e = b * CH + i * 256 + tid;
        if (e < E) {
            int s = srcE[e], d = dstE[e];
            int bin = batch[d];
            int old = atomicAdd(&lc[bin], 1);
            pairs[lstart[bin] + old] = make_int2(s, d);
        }
    }
}

// one block per graph: node-level CSR built in LDS -> global cnt/excl/srcs
__global__ __launch_bounds__(512) void k_csr_local(const int2* __restrict__ pairs,
                                                   const int* __restrict__ boff,
                                                   const int* __restrict__ batch,
                                                   int E, int N, int G,
                                                   int* __restrict__ cnt, int* __restrict__ excl,
                                                   int* __restrict__ srcs) {
    __shared__ int lcnt[512];
    __shared__ int buf[512];
    __shared__ int lcur[512];
    int g = blockIdx.x, t = threadIdx.x;
    // node range [ns, ne): lower_bound on sorted batch
    int lo = 0, hi = N;
    while (lo < hi) { int mid = (lo + hi) >> 1; if (batch[mid] < g) lo = mid + 1; else hi = mid; }
    int ns = lo;
    hi = N;
    while (lo < hi) { int mid = (lo + hi) >> 1; if (batch[mid] < g + 1) lo = mid + 1; else hi = mid; }
    int ne = lo;
    int lnodes = ne - ns;
    int es = boff[g];
    int ee = (g + 1 < G) ? boff[g + 1] : E;

    lcnt[t] = 0;
    __syncthreads();
    for (int e = es + t; e < ee; e += 512) atomicAdd(&lcnt[pairs[e].y - ns], 1);
    __syncthreads();
    int v = lcnt[t];
    buf[t] = v;
    __syncthreads();
    for (int off = 1; off < 512; off <<= 1) {
        int u = (t >= off) ? buf[t - off] : 0;
        __syncthreads();
        buf[t] += u;
        __syncthreads();
    }
    int lex = buf[t] - v;        // exclusive
    lcur[t] = lex;
    if (t < lnodes) {
        cnt[ns + t] = v;
        excl[ns + t] = es + lex;
    }
    __syncthreads();
    for (int e = es + t; e < ee; e += 512) {
        int2 p = pairs[e];
        int pos = atomicAdd(&lcur[p.y - ns], 1);
        srcs[es + pos] = p.x;
    }
}

// ---------------- layer 1 gather: 2 nodes/wave, 32 lanes/node, float2/lane ----------------
// chain 0 initialized with the self-loop (self-loops excluded from CSR)
__global__ void k_gather1(const int* __restrict__ srcs, const int* __restrict__ excl,
                          const int* __restrict__ cnt,
                          const float* __restrict__ asrc1, const float* __restrict__ adst1,
                          const float* __restrict__ h1, float* __restrict__ agg, int N) {
    int tid = blockIdx.x * 256 + threadIdx.x;
    int wave = tid >> 6;
    int lane = threadIdx.x & 63;
    int half = lane >> 5;
    int l = lane & 31;
    int wid = wave * 2 + half;
    if (wid >= N) return;
    int h = l >> 2;
    int c0 = l * 2;

    int beg = excl[wid];
    int cw  = cnt[wid];
    const int* sp = srcs + beg;
    float adh = adst1[wid * 8 + h];

    // self-loop init
    float2 gs = *(const float2*)&h1[(size_t)wid * 64 + c0];
    float m0 = LRELU(asrc1[wid * 8 + h] + adh), d0 = 1.f, ax0 = gs.x, ay0 = gs.y;
    float m1 = -INFINITY, d1 = 0.f, ax1 = 0.f, ay1 = 0.f;
    float m2 = -INFINITY, d2 = 0.f, ax2 = 0.f, ay2 = 0.f;
    float m3 = -INFINITY, d3 = 0.f, ax3 = 0.f, ay3 = 0.f;

    int i = 0;
    for (; i + 4 <= cw; i += 4) {
        int s0 = sp[i], s1 = sp[i + 1], s2 = sp[i + 2], s3 = sp[i + 3];
        float e0 = LRELU(asrc1[s0 * 8 + h] + adh);
        float e1 = LRELU(asrc1[s1 * 8 + h] + adh);
        float e2 = LRELU(asrc1[s2 * 8 + h] + adh);
        float e3 = LRELU(asrc1[s3 * 8 + h] + adh);
        float2 g0 = *(const float2*)&h1[(size_t)s0 * 64 + c0];
        float2 g1 = *(const float2*)&h1[(size_t)s1 * 64 + c0];
        float2 g2 = *(const float2*)&h1[(size_t)s2 * 64 + c0];
        float2 g3 = *(const float2*)&h1[(size_t)s3 * 64 + c0];
        UPD2(m0, d0, ax0, ay0, e0, g0.x, g0.y);
        UPD2(m1, d1, ax1, ay1, e1, g1.x, g1.y);
        UPD2(m2, d2, ax2, ay2, e2, g2.x, g2.y);
        UPD2(m3, d3, ax3, ay3, e3, g3.x, g3.y);
    }
    for (; i < cw; ++i) {
        int s = sp[i];
        float ev = LRELU(asrc1[s * 8 + h] + adh);
        float2 gv = *(const float2*)&h1[(size_t)s * 64 + c0];
        UPD2(m0, d0, ax0, ay0, ev, gv.x, gv.y);
    }
    float mM = fmaxf(fmaxf(m0, m1), fmaxf(m2, m3));
    float w0 = fexp2(m0 - mM), w1 = fexp2(m1 - mM);
    float w2 = fexp2(m2 - mM), w3 = fexp2(m3 - mM);
    float den = d0 * w0 + d1 * w1 + d2 * w2 + d3 * w3;
    float inv = 1.f / (den + 1e-16f);
    float2 r;
    r.x = (ax0 * w0 + ax1 * w1 + ax2 * w2 + ax3 * w3) * inv;
    r.y = (ay0 * w0 + ay1 * w1 + ay2 * w2 + ay3 * w3) * inv;
    *(float2*)&agg[(size_t)wid * 64 + c0] = r;
}

// out1 = elu(agg + b1); h2 = out1 @ W2 (64x10); layer-2 alpha dots (x log2e)
__global__ void k_fin1(const float* __restrict__ agg, const float* __restrict__ b1,
                       const float* __restrict__ W2,
                       const float* __restrict__ a_src2, const float* __restrict__ a_dst2,
                       float* __restrict__ h2, float* __restrict__ asrc2,
                       float* __restrict__ adst2, int N) {
    int n = blockIdx.x * 256 + threadIdx.x;
    if (n >= N) return;
    float acc[10];
#pragma unroll
    for (int j = 0; j < 10; ++j) acc[j] = 0.f;
    const float* ar = agg + (size_t)n * 64;
#pragma unroll 8
    for (int k = 0; k < 64; ++k) {
        float r = ar[k] + b1[k];
        r = r > 0.f ? r : expm1f(r);   // elu
#pragma unroll
        for (int j = 0; j < 10; ++j) acc[j] = fmaf(r, W2[k * 10 + j], acc[j]);
    }
    float s = 0.f, d = 0.f;
#pragma unroll
    for (int j = 0; j < 10; ++j) {
        h2[(size_t)n * 10 + j] = acc[j];
        s = fmaf(acc[j], a_src2[j], s);
        d = fmaf(acc[j], a_dst2[j], d);
    }
    asrc2[n] = s * L2E;
    adst2[n] = d * L2E;
}

// ---------------- layer 2 gather: 4 nodes/wave, 16 lanes/node ----------------
__global__ void k_gather2(const int* __restrict__ srcs, const int* __restrict__ excl,
                          const int* __restrict__ cnt,
                          const float* __restrict__ asrc2, const float* __restrict__ adst2,
                          const float* __restrict__ h2, float* __restrict__ agg2, int N) {
    int tid = blockIdx.x * 256 + threadIdx.x;
    int wave = tid >> 6;
    int lane = threadIdx.x & 63;
    int q = lane >> 4;
    int l = lane & 15;
    int wid = wave * 4 + q;
    if (wid >= N) return;

    int beg = excl[wid];
    int cw  = cnt[wid];
    const int* sp = srcs + beg;
    float adn = adst2[wid];
    bool ld = l < 10;

    // self-loop init
    float m0 = LRELU(asrc2[wid] + adn), d0 = 1.f;
    float a0 = ld ? h2[(size_t)wid * 10 + l] : 0.f;
    float m1 = -INFINITY, d1 = 0.f, a1 = 0.f;
    float m2 = -INFINITY, d2 = 0.f, a2 = 0.f;
    float m3 = -INFINITY, d3 = 0.f, a3 = 0.f;

    int i = 0;
    for (; i + 4 <= cw; i += 4) {
        int s0 = sp[i], s1 = sp[i + 1], s2 = sp[i + 2], s3 = sp[i + 3];
        float e0 = LRELU(asrc2[s0] + adn);
        float e1 = LRELU(asrc2[s1] + adn);
        float e2 = LRELU(asrc2[s2] + adn);
        float e3 = LRELU(asrc2[s3] + adn);
        float g0 = ld ? h2[(size_t)s0 * 10 + l] : 0.f;
        float g1 = ld ? h2[(size_t)s1 * 10 + l] : 0.f;
        float g2 = ld ? h2[(size_t)s2 * 10 + l] : 0.f;
        float g3 = ld ? h2[(size_t)s3 * 10 + l] : 0.f;
        UPD1(m0, d0, a0, e0, g0);
        UPD1(m1, d1, a1, e1, g1);
        UPD1(m2, d2, a2, e2, g2);
        UPD1(m3, d3, a3, e3, g3);
    }
    for (; i < cw; ++i) {
        int s = sp[i];
        float ev = LRELU(asrc2[s] + adn);
        float gv = ld ? h2[(size_t)s * 10 + l] : 0.f;
        UPD1(m0, d0, a0, ev, gv);
    }
    float mM = fmaxf(fmaxf(m0, m1), fmaxf(m2, m3));
    float w0 = fexp2(m0 - mM), w1 = fexp2(m1 - mM);
    float w2 = fexp2(m2 - mM), w3 = fexp2(m3 - mM);
    float den = d0 * w0 + d1 * w1 + d2 * w2 + d3 * w3;
    float acc = a0 * w0 + a1 * w1 + a2 * w2 + a3 * w3;
    if (ld) agg2[(size_t)wid * 10 + l] = acc / (den + 1e-16f);
}

// ---------------- pool (+bias) + log_softmax; block per graph ----------------
__global__ void k_pool_final(const float* __restrict__ agg2, const float* __restrict__ b2,
                             const int* __restrict__ batch, float* __restrict__ out,
                             int N, int G) {
    int g = blockIdx.x;
    int lo = 0, hi = N;
    while (lo < hi) { int mid = (lo + hi) >> 1; if (batch[mid] < g) lo = mid + 1; else hi = mid; }
    int s = lo;
    lo = s; hi = N;
    while (lo < hi) { int mid = (lo + hi) >> 1; if (batch[mid] < g + 1) lo = mid + 1; else hi = mid; }
    int e = lo;
    int tid = threadIdx.x;
    float acc[10];
#pragma unroll
    for (int j = 0; j < 10; ++j) acc[j] = 0.f;
    for (int n = s + tid; n < e; n += 256) {
        const float* r = agg2 + (size_t)n * 10;
#pragma unroll
        for (int j = 0; j < 10; ++j) acc[j] += r[j];
    }
    __shared__ float red[256 * 10];
#pragma unroll
    for (int j = 0; j < 10; ++j) red[tid * 10 + j] = acc[j];
    __syncthreads();
    for (int st = 128; st > 0; st >>= 1) {
        if (tid < st)
#pragma unroll
            for (int j = 0; j < 10; ++j) red[tid * 10 + j] += red[(tid + st) * 10 + j];
        __syncthreads();
    }
    if (tid == 0) {
        int c = e - s;
        float v[10], m = -1e30f;
#pragma unroll
        for (int j = 0; j < 10; ++j) {
            v[j] = (c > 0) ? red[j] / (float)c + b2[j] : 0.f;
            m = fmaxf(m, v[j]);
        }
        float ssum = 0.f;
#pragma unroll
        for (int j = 0; j < 10; ++j) ssum += expf(v[j] - m);
        float ls = logf(ssum);
#pragma unroll
        for (int j = 0; j < 10; ++j) out[(size_t)g * 10 + j] = v[j] - m - ls;
    }
}

extern "C" void kernel_launch(void* const* d_in, const int* in_sizes, int n_in,
                              void* d_out, int out_size, void* d_ws, size_t ws_size,
                              hipStream_t stream) {
    const float* x     = (const float*)d_in[0];
    const int*   ei    = (const int*)d_in[1];
    const int*   batch = (const int*)d_in[2];
    const float* W1    = (const float*)d_in[3];
    const float* as1w  = (const float*)d_in[4];
    const float* ad1w  = (const float*)d_in[5];
    const float* b1    = (const float*)d_in[6];
    const float* W2    = (const float*)d_in[7];
    const float* as2w  = (const float*)d_in[8];
    const float* ad2w  = (const float*)d_in[9];
    const float* b2    = (const float*)d_in[10];

    const int N  = in_sizes[0] / 128;
    const int E  = in_sizes[1] / 2;
    const int G  = out_size / 10;
    const int* srcE = ei;
    const int* dstE = ei + E;

    auto cdiv = [](long long a, long long b) { return (int)((a + b - 1) / b); };
    const int NB = cdiv(E, CH);            // bucket-build blocks (<=512)

    // ---- workspace layout ----
    size_t Nz = (size_t)N;
    float* h1    = (float*)d_ws;           // N*64
    float* agg2  = h1;                     // ALIAS (post fin1)
    float* asrc1 = h1 + Nz * 64;           // N*8
    float* adst1 = asrc1 + Nz * 8;         // N*8
    float* h2    = adst1 + Nz * 8;         // N*10
    float* asrc2 = h2 + Nz * 10;           // N
    float* adst2 = asrc2 + Nz;             // N
    float* agg1  = adst2 + Nz;             // N*64
    int2*  pairs = (int2*)agg1;            // ALIAS: pairs (E*8B) dead before gather1 writes agg1
    int* cntA    = (int*)(agg1 + Nz * 64); // N
    int* exclA   = cntA + Nz;              // N
    int* srcsA   = exclA + Nz;             // E
    int* bhA     = srcsA + E;              // 512*NB
    int* pstartA = bhA + (size_t)512 * NB; // 512*NB
    int* totalA  = pstartA + (size_t)512 * NB; // 512
    int* boffA   = totalA + 512;           // 512

    const int B = 256;

    // layer-1 GEMM (+alpha dots)
    k_gemm1<<<cdiv(N, 64), B, 0, stream>>>(x, W1, as1w, ad1w, h1, asrc1, adst1, N);

    // graph-bucket CSR build (no global atomics)
    k_bhist<<<NB, B, 0, stream>>>(dstE, batch, E, NB, G, bhA);
    k_mscan<<<512, 512, 0, stream>>>(bhA, NB, pstartA, totalA);
    k_scan_top<<<1, 1024, 0, stream>>>(totalA, G, boffA);
    k_bscatter<<<NB, B, 0, stream>>>(srcE, dstE, batch, boffA, pstartA, E, NB, G, pairs);
    k_csr_local<<<G, 512, 0, stream>>>(pairs, boffA, batch, E, N, G, cntA, exclA, srcsA);

    // layer 1 gather (self-loop via init)
    k_gather1<<<cdiv(N, 8), B, 0, stream>>>(srcsA, exclA, cntA, asrc1, adst1, h1, agg1, N);
    k_fin1<<<cdiv(N, B), B, 0, stream>>>(agg1, b1, W2, as2w, ad2w, h2, asrc2, adst2, N);

    // layer 2 gather (agg2 aliases dead h1)
    k_gather2<<<cdiv(N, 16), B, 0, stream>>>(srcsA, exclA, cntA, asrc2, adst2, h2, agg2, N);

    // pool + log_softmax
    k_pool_final<<<G, B, 0, stream>>>(agg2, b2, batch, (float*)d_out, N, G);
}

// Round 8
// 231.519 us; speedup vs baseline: 8.3714x; 1.1000x over previous
//
#include <hip/hip_runtime.h>
#include <math.h>

#define L2E 1.44269504088896f
#define LRELU(v) fmaxf((v), 0.2f * (v))

__device__ __forceinline__ float fexp2(float v) { return __builtin_amdgcn_exp2f(v); }

// bf16 helpers (RNE pack, exact unpack)
__device__ __forceinline__ unsigned short f2bf(float f) {
    unsigned u = __float_as_uint(f);
    u += 0x7FFFu + ((u >> 16) & 1u);
    return (unsigned short)(u >> 16);
}
__device__ __forceinline__ float bf2f(unsigned short b) {
    return __uint_as_float((unsigned)b << 16);
}

// base-2 online-softmax update, 2 channels per lane
#define UPD2(mm, dd, ax, ay, ev, gx, gy)   \
    {                                      \
        float mn_ = fmaxf(mm, ev);         \
        float sc_ = fexp2(mm - mn_);       \
        float w_  = fexp2(ev - mn_);       \
        dd = dd * sc_ + w_;                \
        ax = ax * sc_ + w_ * (gx);         \
        ay = ay * sc_ + w_ * (gy);         \
        mm = mn_;                          \
    }
#define UPD1(mm, dd, aa, ev, hv)           \
    {                                      \
        float mn_ = fmaxf(mm, ev);         \
        float sc_ = fexp2(mm - mn_);       \
        float w_  = fexp2(ev - mn_);       \
        dd = dd * sc_ + w_;                \
        aa = aa * sc_ + w_ * (hv);         \
        mm = mn_;                          \
    }

#define CH 4096   // edges per bucket-build block

// ---------------- layer-1 GEMM + fused alpha dots (x log2e); h1 out in bf16 ----------------
__global__ __launch_bounds__(256) void k_gemm1(
        const float* __restrict__ x, const float* __restrict__ W,
        const float* __restrict__ a_src, const float* __restrict__ a_dst,
        unsigned short* __restrict__ h1b, unsigned short* __restrict__ asrcb,
        float* __restrict__ adst, int N) {
    __shared__ float Wl[128 * 64];
    int tid = threadIdx.x;
    {
        const float4* W4 = (const float4*)W;
        float4* Wl4 = (float4*)Wl;
#pragma unroll
        for (int i = 0; i < 8; ++i) Wl4[tid + 256 * i] = W4[tid + 256 * i];
    }
    __syncthreads();

    int g = tid >> 3, h = tid & 7;
    int n0 = blockIdx.x * 64 + g * 2;
    int n1 = n0 + 1;
    bool v0 = n0 < N, v1 = n1 < N;
    const float4* x4 = (const float4*)x;

    float acca[8], accb[8];
#pragma unroll
    for (int c = 0; c < 8; ++c) { acca[c] = 0.f; accb[c] = 0.f; }

    const float4 z4 = {0.f, 0.f, 0.f, 0.f};
#pragma unroll 4
    for (int kk = 0; kk < 32; ++kk) {
        float4 xa = v0 ? x4[(size_t)n0 * 32 + kk] : z4;
        float4 xb = v1 ? x4[(size_t)n1 * 32 + kk] : z4;
#pragma unroll
        for (int j = 0; j < 4; ++j) {
            int k = kk * 4 + j;
            const float* wr = &Wl[k * 64 + h * 8];
            float xav = ((const float*)&xa)[j];
            float xbv = ((const float*)&xb)[j];
#pragma unroll
            for (int c = 0; c < 8; ++c) {
                float wv = wr[c];
                acca[c] = fmaf(xav, wv, acca[c]);
                accb[c] = fmaf(xbv, wv, accb[c]);
            }
        }
    }

    const float* as = a_src + h * 8;
    const float* ad = a_dst + h * 8;
    if (v0) {
        float s = 0.f, d = 0.f;
        uint4 pk;
        unsigned* pw = (unsigned*)&pk;
#pragma unroll
        for (int c = 0; c < 8; c += 2) {
            s = fmaf(acca[c], as[c], s);     d = fmaf(acca[c], ad[c], d);
            s = fmaf(acca[c+1], as[c+1], s); d = fmaf(acca[c+1], ad[c+1], d);
            pw[c >> 1] = (unsigned)f2bf(acca[c]) | ((unsigned)f2bf(acca[c+1]) << 16);
        }
        *(uint4*)&h1b[(size_t)n0 * 64 + h * 8] = pk;
        asrcb[n0 * 8 + h] = f2bf(s * L2E);
        adst[n0 * 8 + h] = d * L2E;
    }
    if (v1) {
        float s = 0.f, d = 0.f;
        uint4 pk;
        unsigned* pw = (unsigned*)&pk;
#pragma unroll
        for (int c = 0; c < 8; c += 2) {
            s = fmaf(accb[c], as[c], s);     d = fmaf(accb[c], ad[c], d);
            s = fmaf(accb[c+1], as[c+1], s); d = fmaf(accb[c+1], ad[c+1], d);
            pw[c >> 1] = (unsigned)f2bf(accb[c]) | ((unsigned)f2bf(accb[c+1]) << 16);
        }
        *(uint4*)&h1b[(size_t)n1 * 64 + h * 8] = pk;
        asrcb[n1 * 8 + h] = f2bf(s * L2E);
        adst[n1 * 8 + h] = d * L2E;
    }
}

// ---------------- graph-bucket sort (zero global atomics) ----------------

__global__ __launch_bounds__(256) void k_bhist(const int* __restrict__ dstE,
                                               const int* __restrict__ batch,
                                               int E, int NB, int G, int* __restrict__ bh) {
    __shared__ int lh[512];
    int tid = threadIdx.x, b = blockIdx.x;
    lh[tid] = 0; lh[tid + 256] = 0;
    __syncthreads();
#pragma unroll
    for (int i = 0; i < CH / 256; ++i) {
        int e = b * CH + i * 256 + tid;
        if (e < E) atomicAdd(&lh[batch[dstE[e]]], 1);
    }
    __syncthreads();
    if (tid < G)       bh[(size_t)tid * NB + b] = lh[tid];
    if (tid + 256 < G) bh[(size_t)(tid + 256) * NB + b] = lh[tid + 256];
}

__global__ __launch_bounds__(512) void k_mscan(const int* __restrict__ bh, int NB,
                                               int* __restrict__ pstart, int* __restrict__ total) {
    __shared__ int buf[512];
    int bin = blockIdx.x, t = threadIdx.x;
    int v = (t < NB) ? bh[(size_t)bin * NB + t] : 0;
    buf[t] = v;
    __syncthreads();
    for (int off = 1; off < 512; off <<= 1) {
        int u = (t >= off) ? buf[t - off] : 0;
        __syncthreads();
        buf[t] += u;
        __syncthreads();
    }
    if (t < NB) pstart[(size_t)bin * NB + t] = buf[t] - v;
    if (t == 511) total[bin] = buf[511];
}

__global__ __launch_bounds__(1024) void k_scan_top(const int* __restrict__ total, int nb,
                                                   int* __restrict__ boff) {
    __shared__ int buf[1024];
    int t = threadIdx.x;
    int v = (t < nb) ? total[t] : 0;
    buf[t] = v;
    __syncthreads();
    for (int off = 1; off < 1024; off <<= 1) {
        int u = (t >= off) ? buf[t - off] : 0;
        __syncthreads();
        buf[t] += u;
        __syncthreads();
    }
    if (t < nb) boff[t] = buf[t] - v;
}

__global__ __launch_bounds__(256) void k_bscatter(const int* __restrict__ srcE,
                                                  const int* __restrict__ dstE,
                                                  const int* __restrict__ batch,
                                                  const int* __restrict__ boff,
                                                  const int* __restrict__ pstart,
                                                  int E, int NB, int G, int2* __restrict__ pairs) {
    __shared__ int lstart[512];
    __shared__ int lc[512];
    int tid = threadIdx.x, b = blockIdx.x;
#pragma unroll
    for (int j = tid; j < 512; j += 256) {
        lstart[j] = (j < G) ? boff[j] + pstart[(size_t)j * NB + b] : 0;
        lc[j] = 0;
    }
    __syncthreads();
#pragma unroll
    for (int i = 0; i < CH / 256; ++i) {
        int e = b * CH + i * 256 + tid;
        if (e < E) {
            int s = srcE[e], d = dstE[e];
            int bin = batch[d];
            int old = atomicAdd(&lc[bin], 1);
            pairs[lstart[bin] + old] = make_int2(s, d);
        }
    }
}

__global__ __launch_bounds__(512) void k_csr_local(const int2* __restrict__ pairs,
                                                   const int* __restrict__ boff,
                                                   const int* __restrict__ batch,
                                                   int E, int N, int G,
                                                   int* __restrict__ cnt, int* __restrict__ excl,
                                                   int* __restrict__ srcs) {
    __shared__ int lcnt[512];
    __shared__ int buf[512];
    __shared__ int lcur[512];
    int g = blockIdx.x, t = threadIdx.x;
    int lo = 0, hi = N;
    while (lo < hi) { int mid = (lo + hi) >> 1; if (batch[mid] < g) lo = mid + 1; else hi = mid; }
    int ns = lo;
    hi = N;
    while (lo < hi) { int mid = (lo + hi) >> 1; if (batch[mid] < g + 1) lo = mid + 1; else hi = mid; }
    int ne = lo;
    int lnodes = ne - ns;
    int es = boff[g];
    int ee = (g + 1 < G) ? boff[g + 1] : E;

    lcnt[t] = 0;
    __syncthreads();
    for (int e = es + t; e < ee; e += 512) atomicAdd(&lcnt[pairs[e].y - ns], 1);
    __syncthreads();
    int v = lcnt[t];
    buf[t] = v;
    __syncthreads();
    for (int off = 1; off < 512; off <<= 1) {
        int u = (t >= off) ? buf[t - off] : 0;
        __syncthreads();
        buf[t] += u;
        __syncthreads();
    }
    int lex = buf[t] - v;
    lcur[t] = lex;
    if (t < lnodes) {
        cnt[ns + t] = v;
        excl[ns + t] = es + lex;
    }
    __syncthreads();
    for (int e = es + t; e < ee; e += 512) {
        int2 p = pairs[e];
        int pos = atomicAdd(&lcur[p.y - ns], 1);
        srcs[es + pos] = p.x;
    }
}

// ---------------- layer 1 gather: 2 nodes/wave, 32 lanes/node, bf16x2/lane ----------------
__global__ void k_gather1(const int* __restrict__ srcs, const int* __restrict__ excl,
                          const int* __restrict__ cnt,
                          const unsigned short* __restrict__ asrcb, const float* __restrict__ adst1,
                          const unsigned short* __restrict__ h1b, float* __restrict__ agg, int N) {
    int tid = blockIdx.x * 256 + threadIdx.x;
    int wave = tid >> 6;
    int lane = threadIdx.x & 63;
    int half = lane >> 5;
    int l = lane & 31;
    int wid = wave * 2 + half;
    if (wid >= N) return;
    int h = l >> 2;
    int c0 = l * 2;

    int beg = excl[wid];
    int cw  = cnt[wid];
    const int* sp = srcs + beg;
    float adh = adst1[wid * 8 + h];

    // self-loop init
    ushort2 gsu = *(const ushort2*)&h1b[(size_t)wid * 64 + c0];
    float m0 = LRELU(bf2f(asrcb[wid * 8 + h]) + adh), d0 = 1.f;
    float ax0 = bf2f(gsu.x), ay0 = bf2f(gsu.y);
    float m1 = -INFINITY, d1 = 0.f, ax1 = 0.f, ay1 = 0.f;
    float m2 = -INFINITY, d2 = 0.f, ax2 = 0.f, ay2 = 0.f;
    float m3 = -INFINITY, d3 = 0.f, ax3 = 0.f, ay3 = 0.f;

    int i = 0;
    for (; i + 4 <= cw; i += 4) {
        int s0 = sp[i], s1 = sp[i + 1], s2 = sp[i + 2], s3 = sp[i + 3];
        float e0 = LRELU(bf2f(asrcb[s0 * 8 + h]) + adh);
        float e1 = LRELU(bf2f(asrcb[s1 * 8 + h]) + adh);
        float e2 = LRELU(bf2f(asrcb[s2 * 8 + h]) + adh);
        float e3 = LRELU(bf2f(asrcb[s3 * 8 + h]) + adh);
        ushort2 g0 = *(const ushort2*)&h1b[(size_t)s0 * 64 + c0];
        ushort2 g1 = *(const ushort2*)&h1b[(size_t)s1 * 64 + c0];
        ushort2 g2 = *(const ushort2*)&h1b[(size_t)s2 * 64 + c0];
        ushort2 g3 = *(const ushort2*)&h1b[(size_t)s3 * 64 + c0];
        UPD2(m0, d0, ax0, ay0, e0, bf2f(g0.x), bf2f(g0.y));
        UPD2(m1, d1, ax1, ay1, e1, bf2f(g1.x), bf2f(g1.y));
        UPD2(m2, d2, ax2, ay2, e2, bf2f(g2.x), bf2f(g2.y));
        UPD2(m3, d3, ax3, ay3, e3, bf2f(g3.x), bf2f(g3.y));
    }
    for (; i < cw; ++i) {
        int s = sp[i];
        float ev = LRELU(bf2f(asrcb[s * 8 + h]) + adh);
        ushort2 gv = *(const ushort2*)&h1b[(size_t)s * 64 + c0];
        UPD2(m0, d0, ax0, ay0, ev, bf2f(gv.x), bf2f(gv.y));
    }
    float mM = fmaxf(fmaxf(m0, m1), fmaxf(m2, m3));
    float w0 = fexp2(m0 - mM), w1 = fexp2(m1 - mM);
    float w2 = fexp2(m2 - mM), w3 = fexp2(m3 - mM);
    float den = d0 * w0 + d1 * w1 + d2 * w2 + d3 * w3;
    float inv = 1.f / (den + 1e-16f);
    float2 r;
    r.x = (ax0 * w0 + ax1 * w1 + ax2 * w2 + ax3 * w3) * inv;
    r.y = (ay0 * w0 + ay1 * w1 + ay2 * w2 + ay3 * w3) * inv;
    *(float2*)&agg[(size_t)wid * 64 + c0] = r;
}

// out1 = elu(agg + b1); h2 = out1 @ W2 (64x10) -> bf16; layer-2 alpha dots (x log2e)
__global__ void k_fin1(const float* __restrict__ agg, const float* __restrict__ b1,
                       const float* __restrict__ W2,
                       const float* __restrict__ a_src2, const float* __restrict__ a_dst2,
                       unsigned short* __restrict__ h2b, unsigned short* __restrict__ asrc2b,
                       float* __restrict__ adst2, int N) {
    int n = blockIdx.x * 256 + threadIdx.x;
    if (n >= N) return;
    float acc[10];
#pragma unroll
    for (int j = 0; j < 10; ++j) acc[j] = 0.f;
    const float* ar = agg + (size_t)n * 64;
#pragma unroll 8
    for (int k = 0; k < 64; ++k) {
        float r = ar[k] + b1[k];
        r = r > 0.f ? r : expm1f(r);   // elu
#pragma unroll
        for (int j = 0; j < 10; ++j) acc[j] = fmaf(r, W2[k * 10 + j], acc[j]);
    }
    float s = 0.f, d = 0.f;
    unsigned pw[5];
#pragma unroll
    for (int j = 0; j < 10; j += 2) {
        s = fmaf(acc[j], a_src2[j], s);     d = fmaf(acc[j], a_dst2[j], d);
        s = fmaf(acc[j+1], a_src2[j+1], s); d = fmaf(acc[j+1], a_dst2[j+1], d);
        pw[j >> 1] = (unsigned)f2bf(acc[j]) | ((unsigned)f2bf(acc[j+1]) << 16);
    }
    unsigned* hw = (unsigned*)&h2b[(size_t)n * 10];
#pragma unroll
    for (int j = 0; j < 5; ++j) hw[j] = pw[j];
    asrc2b[n] = f2bf(s * L2E);
    adst2[n] = d * L2E;
}

// ---------------- layer 2 gather: 4 nodes/wave, 16 lanes/node ----------------
__global__ void k_gather2(const int* __restrict__ srcs, const int* __restrict__ excl,
                          const int* __restrict__ cnt,
                          const unsigned short* __restrict__ asrc2b, const float* __restrict__ adst2,
                          const unsigned short* __restrict__ h2b, float* __restrict__ agg2, int N) {
    int tid = blockIdx.x * 256 + threadIdx.x;
    int wave = tid >> 6;
    int lane = threadIdx.x & 63;
    int q = lane >> 4;
    int l = lane & 15;
    int wid = wave * 4 + q;
    if (wid >= N) return;

    int beg = excl[wid];
    int cw  = cnt[wid];
    const int* sp = srcs + beg;
    float adn = adst2[wid];
    bool ld = l < 10;

    // self-loop init
    float m0 = LRELU(bf2f(asrc2b[wid]) + adn), d0 = 1.f;
    float a0 = ld ? bf2f(h2b[(size_t)wid * 10 + l]) : 0.f;
    float m1 = -INFINITY, d1 = 0.f, a1 = 0.f;
    float m2 = -INFINITY, d2 = 0.f, a2 = 0.f;
    float m3 = -INFINITY, d3 = 0.f, a3 = 0.f;

    int i = 0;
    for (; i + 4 <= cw; i += 4) {
        int s0 = sp[i], s1 = sp[i + 1], s2 = sp[i + 2], s3 = sp[i + 3];
        float e0 = LRELU(bf2f(asrc2b[s0]) + adn);
        float e1 = LRELU(bf2f(asrc2b[s1]) + adn);
        float e2 = LRELU(bf2f(asrc2b[s2]) + adn);
        float e3 = LRELU(bf2f(asrc2b[s3]) + adn);
        float g0 = ld ? bf2f(h2b[(size_t)s0 * 10 + l]) : 0.f;
        float g1 = ld ? bf2f(h2b[(size_t)s1 * 10 + l]) : 0.f;
        float g2 = ld ? bf2f(h2b[(size_t)s2 * 10 + l]) : 0.f;
        float g3 = ld ? bf2f(h2b[(size_t)s3 * 10 + l]) : 0.f;
        UPD1(m0, d0, a0, e0, g0);
        UPD1(m1, d1, a1, e1, g1);
        UPD1(m2, d2, a2, e2, g2);
        UPD1(m3, d3, a3, e3, g3);
    }
    for (; i < cw; ++i) {
        int s = sp[i];
        float ev = LRELU(bf2f(asrc2b[s]) + adn);
        float gv = ld ? bf2f(h2b[(size_t)s * 10 + l]) : 0.f;
        UPD1(m0, d0, a0, ev, gv);
    }
    float mM = fmaxf(fmaxf(m0, m1), fmaxf(m2, m3));
    float w0 = fexp2(m0 - mM), w1 = fexp2(m1 - mM);
    float w2 = fexp2(m2 - mM), w3 = fexp2(m3 - mM);
    float den = d0 * w0 + d1 * w1 + d2 * w2 + d3 * w3;
    float acc = a0 * w0 + a1 * w1 + a2 * w2 + a3 * w3;
    if (ld) agg2[(size_t)wid * 10 + l] = acc / (den + 1e-16f);
}

// ---------------- pool (+bias) + log_softmax; block per graph ----------------
__global__ void k_pool_final(const float* __restrict__ agg2, const float* __restrict__ b2,
                             const int* __restrict__ batch, float* __restrict__ out,
                             int N, int G) {
    int g = blockIdx.x;
    int lo = 0, hi = N;
    while (lo < hi) { int mid = (lo + hi) >> 1; if (batch[mid] < g) lo = mid + 1; else hi = mid; }
    int s = lo;
    lo = s; hi = N;
    while (lo < hi) { int mid = (lo + hi) >> 1; if (batch[mid] < g + 1) lo = mid + 1; else hi = mid; }
    int e = lo;
    int tid = threadIdx.x;
    float acc[10];
#pragma unroll
    for (int j = 0; j < 10; ++j) acc[j] = 0.f;
    for (int n = s + tid; n < e; n += 256) {
        const float* r = agg2 + (size_t)n * 10;
#pragma unroll
        for (int j = 0; j < 10; ++j) acc[j] += r[j];
    }
    __shared__ float red[256 * 10];
#pragma unroll
    for (int j = 0; j < 10; ++j) red[tid * 10 + j] = acc[j];
    __syncthreads();
    for (int st = 128; st > 0; st >>= 1) {
        if (tid < st)
#pragma unroll
            for (int j = 0; j < 10; ++j) red[tid * 10 + j] += red[(tid + st) * 10 + j];
        __syncthreads();
    }
    if (tid == 0) {
        int c = e - s;
        float v[10], m = -1e30f;
#pragma unroll
        for (int j = 0; j < 10; ++j) {
            v[j] = (c > 0) ? red[j] / (float)c + b2[j] : 0.f;
            m = fmaxf(m, v[j]);
        }
        float ssum = 0.f;
#pragma unroll
        for (int j = 0; j < 10; ++j) ssum += expf(v[j] - m);
        float ls = logf(ssum);
#pragma unroll
        for (int j = 0; j < 10; ++j) out[(size_t)g * 10 + j] = v[j] - m - ls;
    }
}

extern "C" void kernel_launch(void* const* d_in, const int* in_sizes, int n_in,
                              void* d_out, int out_size, void* d_ws, size_t ws_size,
                              hipStream_t stream) {
    const float* x     = (const float*)d_in[0];
    const int*   ei    = (const int*)d_in[1];
    const int*   batch = (const int*)d_in[2];
    const float* W1    = (const float*)d_in[3];
    const float* as1w  = (const float*)d_in[4];
    const float* ad1w  = (const float*)d_in[5];
    const float* b1    = (const float*)d_in[6];
    const float* W2    = (const float*)d_in[7];
    const float* as2w  = (const float*)d_in[8];
    const float* ad2w  = (const float*)d_in[9];
    const float* b2    = (const float*)d_in[10];

    const int N  = in_sizes[0] / 128;
    const int E  = in_sizes[1] / 2;
    const int G  = out_size / 10;
    const int* srcE = ei;
    const int* dstE = ei + E;

    auto cdiv = [](long long a, long long b) { return (int)((a + b - 1) / b); };
    const int NB = cdiv(E, CH);

    // ---- workspace layout ----
    size_t Nz = (size_t)N;
    unsigned short* h1b = (unsigned short*)d_ws;        // N*64 bf16 (N*32 f32-equiv)
    float* agg2  = (float*)d_ws;                        // ALIAS: h1b dead after gather1
    unsigned short* asrc1b = h1b + Nz * 64;             // N*8 bf16
    float* adst1 = (float*)(asrc1b + Nz * 8);           // N*8 f32
    unsigned short* h2b = (unsigned short*)(adst1 + Nz * 8); // N*10 bf16
    unsigned short* asrc2b = h2b + Nz * 10;             // N bf16
    float* adst2 = (float*)(asrc2b + Nz + (Nz & 1));    // N f32 (align to 4B)
    float* agg1  = adst2 + Nz;                          // N*64 f32
    int2*  pairs = (int2*)agg1;                         // ALIAS: dead before gather1 writes agg1
    int* cntA    = (int*)(agg1 + Nz * 64);              // N
    int* exclA   = cntA + Nz;                           // N
    int* srcsA   = exclA + Nz;                          // E
    int* bhA     = srcsA + E;                           // 512*NB
    int* pstartA = bhA + (size_t)512 * NB;              // 512*NB
    int* totalA  = pstartA + (size_t)512 * NB;          // 512
    int* boffA   = totalA + 512;                        // 512

    const int B = 256;

    // layer-1 GEMM (+alpha dots), bf16 h1
    k_gemm1<<<cdiv(N, 64), B, 0, stream>>>(x, W1, as1w, ad1w, h1b, asrc1b, adst1, N);

    // graph-bucket CSR build (no global atomics)
    k_bhist<<<NB, B, 0, stream>>>(dstE, batch, E, NB, G, bhA);
    k_mscan<<<512, 512, 0, stream>>>(bhA, NB, pstartA, totalA);
    k_scan_top<<<1, 1024, 0, stream>>>(totalA, G, boffA);
    k_bscatter<<<NB, B, 0, stream>>>(srcE, dstE, batch, boffA, pstartA, E, NB, G, pairs);
    k_csr_local<<<G, 512, 0, stream>>>(pairs, boffA, batch, E, N, G, cntA, exclA, srcsA);

    // layer 1 gather (self-loop via init)
    k_gather1<<<cdiv(N, 8), B, 0, stream>>>(srcsA, exclA, cntA, asrc1b, adst1, h1b, agg1, N);
    k_fin1<<<cdiv(N, B), B, 0, stream>>>(agg1, b1, W2, as2w, ad2w, h2b, asrc2b, adst2, N);

    // layer 2 gather (agg2 aliases dead h1b)
    k_gather2<<<cdiv(N, 16), B, 0, stream>>>(srcsA, exclA, cntA, asrc2b, adst2, h2b, agg2, N);

    // pool + log_softmax
    k_pool_final<<<G, B, 0, stream>>>(agg2, b2, batch, (float*)d_out, N, G);
}

// Round 9
// 220.242 us; speedup vs baseline: 8.8000x; 1.0512x over previous
//
#include <hip/hip_runtime.h>
#include <math.h>

#define L2E 1.44269504088896f
#define LRELU(v) fmaxf((v), 0.2f * (v))

__device__ __forceinline__ float fexp2(float v) { return __builtin_amdgcn_exp2f(v); }

// bf16 helpers (RNE pack, exact unpack)
__device__ __forceinline__ unsigned short f2bf(float f) {
    unsigned u = __float_as_uint(f);
    u += 0x7FFFu + ((u >> 16) & 1u);
    return (unsigned short)(u >> 16);
}
__device__ __forceinline__ float bf2f(unsigned short b) {
    return __uint_as_float((unsigned)b << 16);
}

// base-2 online-softmax update, 4 channels (float4 acc)
#define UPD4(mm, dd, AA, ev, GG)           \
    {                                      \
        float mn_ = fmaxf(mm, ev);         \
        float sc_ = fexp2(mm - mn_);       \
        float w_  = fexp2(ev - mn_);       \
        dd = dd * sc_ + w_;                \
        AA.x = AA.x * sc_ + w_ * (GG).x;   \
        AA.y = AA.y * sc_ + w_ * (GG).y;   \
        AA.z = AA.z * sc_ + w_ * (GG).z;   \
        AA.w = AA.w * sc_ + w_ * (GG).w;   \
        mm = mn_;                          \
    }
#define UPD1(mm, dd, aa, ev, hv)           \
    {                                      \
        float mn_ = fmaxf(mm, ev);         \
        float sc_ = fexp2(mm - mn_);       \
        float w_  = fexp2(ev - mn_);       \
        dd = dd * sc_ + w_;                \
        aa = aa * sc_ + w_ * (hv);         \
        mm = mn_;                          \
    }

#define CH 4096   // edges per bucket-build block

__device__ __forceinline__ float4 b4f(ushort4 u) {
    float4 r;
    r.x = bf2f(u.x); r.y = bf2f(u.y); r.z = bf2f(u.z); r.w = bf2f(u.w);
    return r;
}

// ---------------- layer-1 GEMM: 8 nodes/thread (LDS reuse), bf16 h1 out ----------------
__global__ __launch_bounds__(256) void k_gemm1(
        const float* __restrict__ x, const float* __restrict__ W,
        const float* __restrict__ a_src, const float* __restrict__ a_dst,
        unsigned short* __restrict__ h1b, unsigned short* __restrict__ asrcb,
        float* __restrict__ adst, int N) {
    __shared__ float Wl[128 * 64];
    int tid = threadIdx.x;
    {
        const float4* W4 = (const float4*)W;
        float4* Wl4 = (float4*)Wl;
#pragma unroll
        for (int i = 0; i < 8; ++i) Wl4[tid + 256 * i] = W4[tid + 256 * i];
    }
    __syncthreads();

    int g = tid >> 3, h = tid & 7;
    int n0 = blockIdx.x * 256 + g * 8;     // 32 g-slots x 8 nodes = 256 nodes/block
    const float4* x4 = (const float4*)x;

    float acc[8][8];
#pragma unroll
    for (int nn = 0; nn < 8; ++nn)
#pragma unroll
        for (int c = 0; c < 8; ++c) acc[nn][c] = 0.f;

    const float4 z4 = {0.f, 0.f, 0.f, 0.f};
    for (int kk = 0; kk < 32; ++kk) {
        float4 xa[8];
#pragma unroll
        for (int nn = 0; nn < 8; ++nn)
            xa[nn] = (n0 + nn < N) ? x4[(size_t)(n0 + nn) * 32 + kk] : z4;
#pragma unroll
        for (int j = 0; j < 4; ++j) {
            const float* wr = &Wl[(kk * 4 + j) * 64 + h * 8];
            float wv[8];
#pragma unroll
            for (int c = 0; c < 8; ++c) wv[c] = wr[c];
#pragma unroll
            for (int nn = 0; nn < 8; ++nn) {
                float xv = ((const float*)&xa[nn])[j];
#pragma unroll
                for (int c = 0; c < 8; ++c) acc[nn][c] = fmaf(xv, wv[c], acc[nn][c]);
            }
        }
    }

    const float* as = a_src + h * 8;
    const float* ad = a_dst + h * 8;
#pragma unroll
    for (int nn = 0; nn < 8; ++nn) {
        int n = n0 + nn;
        if (n >= N) break;
        float s = 0.f, d = 0.f;
        uint4 pk;
        unsigned* pw = (unsigned*)&pk;
#pragma unroll
        for (int c = 0; c < 8; c += 2) {
            s = fmaf(acc[nn][c], as[c], s);     d = fmaf(acc[nn][c], ad[c], d);
            s = fmaf(acc[nn][c+1], as[c+1], s); d = fmaf(acc[nn][c+1], ad[c+1], d);
            pw[c >> 1] = (unsigned)f2bf(acc[nn][c]) | ((unsigned)f2bf(acc[nn][c+1]) << 16);
        }
        *(uint4*)&h1b[(size_t)n * 64 + h * 8] = pk;
        asrcb[n * 8 + h] = f2bf(s * L2E);
        adst[n * 8 + h] = d * L2E;
    }
}

// ---------------- graph-bucket sort (zero global atomics) ----------------

__global__ __launch_bounds__(256) void k_bhist(const int* __restrict__ dstE,
                                               const int* __restrict__ batch,
                                               int E, int NB, int G, int* __restrict__ bh) {
    __shared__ int lh[512];
    int tid = threadIdx.x, b = blockIdx.x;
    lh[tid] = 0; lh[tid + 256] = 0;
    __syncthreads();
#pragma unroll
    for (int i = 0; i < CH / 256; ++i) {
        int e = b * CH + i * 256 + tid;
        if (e < E) atomicAdd(&lh[batch[dstE[e]]], 1);
    }
    __syncthreads();
    if (tid < G)       bh[(size_t)tid * NB + b] = lh[tid];
    if (tid + 256 < G) bh[(size_t)(tid + 256) * NB + b] = lh[tid + 256];
}

__global__ __launch_bounds__(512) void k_mscan(const int* __restrict__ bh, int NB,
                                               int* __restrict__ pstart, int* __restrict__ total) {
    __shared__ int buf[512];
    int bin = blockIdx.x, t = threadIdx.x;
    int v = (t < NB) ? bh[(size_t)bin * NB + t] : 0;
    buf[t] = v;
    __syncthreads();
    for (int off = 1; off < 512; off <<= 1) {
        int u = (t >= off) ? buf[t - off] : 0;
        __syncthreads();
        buf[t] += u;
        __syncthreads();
    }
    if (t < NB) pstart[(size_t)bin * NB + t] = buf[t] - v;
    if (t == 511) total[bin] = buf[511];
}

__global__ __launch_bounds__(1024) void k_scan_top(const int* __restrict__ total, int nb,
                                                   int* __restrict__ boff) {
    __shared__ int buf[1024];
    int t = threadIdx.x;
    int v = (t < nb) ? total[t] : 0;
    buf[t] = v;
    __syncthreads();
    for (int off = 1; off < 1024; off <<= 1) {
        int u = (t >= off) ? buf[t - off] : 0;
        __syncthreads();
        buf[t] += u;
        __syncthreads();
    }
    if (t < nb) boff[t] = buf[t] - v;
}

__global__ __launch_bounds__(256) void k_bscatter(const int* __restrict__ srcE,
                                                  const int* __restrict__ dstE,
                                                  const int* __restrict__ batch,
                                                  const int* __restrict__ boff,
                                                  const int* __restrict__ pstart,
                                                  int E, int NB, int G, int2* __restrict__ pairs) {
    __shared__ int lstart[512];
    __shared__ int lc[512];
    int tid = threadIdx.x, b = blockIdx.x;
#pragma unroll
    for (int j = tid; j < 512; j += 256) {
        lstart[j] = (j < G) ? boff[j] + pstart[(size_t)j * NB + b] : 0;
        lc[j] = 0;
    }
    __syncthreads();
#pragma unroll
    for (int i = 0; i < CH / 256; ++i) {
        int e = b * CH + i * 256 + tid;
        if (e < E) {
            int s = srcE[e], d = dstE[e];
            int bin = batch[d];
            int old = atomicAdd(&lc[bin], 1);
            pairs[lstart[bin] + old] = make_int2(s, d);
        }
    }
}

__global__ __launch_bounds__(512) void k_csr_local(const int2* __restrict__ pairs,
                                                   const int* __restrict__ boff,
                                                   const int* __restrict__ batch,
                                                   int E, int N, int G,
                                                   int* __restrict__ cnt, int* __restrict__ excl,
                                                   int* __restrict__ srcs) {
    __shared__ int lcnt[512];
    __shared__ int buf[512];
    __shared__ int lcur[512];
    int g = blockIdx.x, t = threadIdx.x;
    int lo = 0, hi = N;
    while (lo < hi) { int mid = (lo + hi) >> 1; if (batch[mid] < g) lo = mid + 1; else hi = mid; }
    int ns = lo;
    hi = N;
    while (lo < hi) { int mid = (lo + hi) >> 1; if (batch[mid] < g + 1) lo = mid + 1; else hi = mid; }
    int ne = lo;
    int lnodes = ne - ns;
    int es = boff[g];
    int ee = (g + 1 < G) ? boff[g + 1] : E;

    lcnt[t] = 0;
    __syncthreads();
    for (int e = es + t; e < ee; e += 512) atomicAdd(&lcnt[pairs[e].y - ns], 1);
    __syncthreads();
    int v = lcnt[t];
    buf[t] = v;
    __syncthreads();
    for (int off = 1; off < 512; off <<= 1) {
        int u = (t >= off) ? buf[t - off] : 0;
        __syncthreads();
        buf[t] += u;
        __syncthreads();
    }
    int lex = buf[t] - v;
    lcur[t] = lex;
    if (t < lnodes) {
        cnt[ns + t] = v;
        excl[ns + t] = es + lex;
    }
    __syncthreads();
    for (int e = es + t; e < ee; e += 512) {
        int2 p = pairs[e];
        int pos = atomicAdd(&lcur[p.y - ns], 1);
        srcs[es + pos] = p.x;
    }
}

// ---------------- layer 1 gather: 4 nodes/wave, 16 lanes/node, bf16x4/lane ----------------
__global__ void k_gather1(const int* __restrict__ srcs, const int* __restrict__ excl,
                          const int* __restrict__ cnt,
                          const unsigned short* __restrict__ asrcb, const float* __restrict__ adst1,
                          const unsigned short* __restrict__ h1b, float* __restrict__ agg, int N) {
    int tid = blockIdx.x * 256 + threadIdx.x;
    int wave = tid >> 6;
    int lane = threadIdx.x & 63;
    int q = lane >> 4;            // node slot
    int l = lane & 15;
    int wid = wave * 4 + q;
    if (wid >= N) return;
    int h = l >> 1;               // head (2 lanes/head)
    int c0 = l * 4;               // channels c0..c0+3

    int beg = excl[wid];
    int cw  = cnt[wid];
    const int* sp = srcs + beg;
    float adh = adst1[wid * 8 + h];

    // self-loop init on chain 0
    float4 A0 = b4f(*(const ushort4*)&h1b[(size_t)wid * 64 + c0]);
    float m0 = LRELU(bf2f(asrcb[wid * 8 + h]) + adh), d0 = 1.f;
    float4 A1 = {0.f, 0.f, 0.f, 0.f}, A2 = A1, A3 = A1;
    float m1 = -INFINITY, d1 = 0.f;
    float m2 = -INFINITY, d2 = 0.f;
    float m3 = -INFINITY, d3 = 0.f;

    int i = 0;
    for (; i + 4 <= cw; i += 4) {
        int s0 = sp[i], s1 = sp[i + 1], s2 = sp[i + 2], s3 = sp[i + 3];
        float e0 = LRELU(bf2f(asrcb[s0 * 8 + h]) + adh);
        float e1 = LRELU(bf2f(asrcb[s1 * 8 + h]) + adh);
        float e2 = LRELU(bf2f(asrcb[s2 * 8 + h]) + adh);
        float e3 = LRELU(bf2f(asrcb[s3 * 8 + h]) + adh);
        float4 g0 = b4f(*(const ushort4*)&h1b[(size_t)s0 * 64 + c0]);
        float4 g1 = b4f(*(const ushort4*)&h1b[(size_t)s1 * 64 + c0]);
        float4 g2 = b4f(*(const ushort4*)&h1b[(size_t)s2 * 64 + c0]);
        float4 g3 = b4f(*(const ushort4*)&h1b[(size_t)s3 * 64 + c0]);
        UPD4(m0, d0, A0, e0, g0);
        UPD4(m1, d1, A1, e1, g1);
        UPD4(m2, d2, A2, e2, g2);
        UPD4(m3, d3, A3, e3, g3);
    }
    for (; i < cw; ++i) {
        int s = sp[i];
        float ev = LRELU(bf2f(asrcb[s * 8 + h]) + adh);
        float4 gv = b4f(*(const ushort4*)&h1b[(size_t)s * 64 + c0]);
        UPD4(m0, d0, A0, ev, gv);
    }
    float mM = fmaxf(fmaxf(m0, m1), fmaxf(m2, m3));
    float w0 = fexp2(m0 - mM), w1 = fexp2(m1 - mM);
    float w2 = fexp2(m2 - mM), w3 = fexp2(m3 - mM);
    float den = d0 * w0 + d1 * w1 + d2 * w2 + d3 * w3;
    float inv = 1.f / (den + 1e-16f);
    float4 r;
    r.x = (A0.x * w0 + A1.x * w1 + A2.x * w2 + A3.x * w3) * inv;
    r.y = (A0.y * w0 + A1.y * w1 + A2.y * w2 + A3.y * w3) * inv;
    r.z = (A0.z * w0 + A1.z * w1 + A2.z * w2 + A3.z * w3) * inv;
    r.w = (A0.w * w0 + A1.w * w1 + A2.w * w2 + A3.w * w3) * inv;
    *(float4*)&agg[(size_t)wid * 64 + c0] = r;
}

// out1 = elu(agg + b1); h2 = out1 @ W2 (64x10) -> bf16; layer-2 alpha dots (x log2e)
__global__ void k_fin1(const float* __restrict__ agg, const float* __restrict__ b1,
                       const float* __restrict__ W2,
                       const float* __restrict__ a_src2, const float* __restrict__ a_dst2,
                       unsigned short* __restrict__ h2b, unsigned short* __restrict__ asrc2b,
                       float* __restrict__ adst2, int N) {
    int n = blockIdx.x * 256 + threadIdx.x;
    if (n >= N) return;
    float acc[10];
#pragma unroll
    for (int j = 0; j < 10; ++j) acc[j] = 0.f;
    const float* ar = agg + (size_t)n * 64;
#pragma unroll 8
    for (int k = 0; k < 64; ++k) {
        float r = ar[k] + b1[k];
        r = r > 0.f ? r : expm1f(r);   // elu
#pragma unroll
        for (int j = 0; j < 10; ++j) acc[j] = fmaf(r, W2[k * 10 + j], acc[j]);
    }
    float s = 0.f, d = 0.f;
    unsigned pw[5];
#pragma unroll
    for (int j = 0; j < 10; j += 2) {
        s = fmaf(acc[j], a_src2[j], s);     d = fmaf(acc[j], a_dst2[j], d);
        s = fmaf(acc[j+1], a_src2[j+1], s); d = fmaf(acc[j+1], a_dst2[j+1], d);
        pw[j >> 1] = (unsigned)f2bf(acc[j]) | ((unsigned)f2bf(acc[j+1]) << 16);
    }
    unsigned* hw = (unsigned*)&h2b[(size_t)n * 10];
#pragma unroll
    for (int j = 0; j < 5; ++j) hw[j] = pw[j];
    asrc2b[n] = f2bf(s * L2E);
    adst2[n] = d * L2E;
}

// ---------------- layer 2 gather: 4 nodes/wave, 16 lanes/node ----------------
__global__ void k_gather2(const int* __restrict__ srcs, const int* __restrict__ excl,
                          const int* __restrict__ cnt,
                          const unsigned short* __restrict__ asrc2b, const float* __restrict__ adst2,
                          const unsigned short* __restrict__ h2b, float* __restrict__ agg2, int N) {
    int tid = blockIdx.x * 256 + threadIdx.x;
    int wave = tid >> 6;
    int lane = threadIdx.x & 63;
    int q = lane >> 4;
    int l = lane & 15;
    int wid = wave * 4 + q;
    if (wid >= N) return;

    int beg = excl[wid];
    int cw  = cnt[wid];
    const int* sp = srcs + beg;
    float adn = adst2[wid];
    bool ld = l < 10;

    float m0 = LRELU(bf2f(asrc2b[wid]) + adn), d0 = 1.f;
    float a0 = ld ? bf2f(h2b[(size_t)wid * 10 + l]) : 0.f;
    float m1 = -INFINITY, d1 = 0.f, a1 = 0.f;
    float m2 = -INFINITY, d2 = 0.f, a2 = 0.f;
    float m3 = -INFINITY, d3 = 0.f, a3 = 0.f;

    int i = 0;
    for (; i + 4 <= cw; i += 4) {
        int s0 = sp[i], s1 = sp[i + 1], s2 = sp[i + 2], s3 = sp[i + 3];
        float e0 = LRELU(bf2f(asrc2b[s0]) + adn);
        float e1 = LRELU(bf2f(asrc2b[s1]) + adn);
        float e2 = LRELU(bf2f(asrc2b[s2]) + adn);
        float e3 = LRELU(bf2f(asrc2b[s3]) + adn);
        float g0 = ld ? bf2f(h2b[(size_t)s0 * 10 + l]) : 0.f;
        float g1 = ld ? bf2f(h2b[(size_t)s1 * 10 + l]) : 0.f;
        float g2 = ld ? bf2f(h2b[(size_t)s2 * 10 + l]) : 0.f;
        float g3 = ld ? bf2f(h2b[(size_t)s3 * 10 + l]) : 0.f;
        UPD1(m0, d0, a0, e0, g0);
        UPD1(m1, d1, a1, e1, g1);
        UPD1(m2, d2, a2, e2, g2);
        UPD1(m3, d3, a3, e3, g3);
    }
    for (; i < cw; ++i) {
        int s = sp[i];
        float ev = LRELU(bf2f(asrc2b[s]) + adn);
        float gv = ld ? bf2f(h2b[(size_t)s * 10 + l]) : 0.f;
        UPD1(m0, d0, a0, ev, gv);
    }
    float mM = fmaxf(fmaxf(m0, m1), fmaxf(m2, m3));
    float w0 = fexp2(m0 - mM), w1 = fexp2(m1 - mM);
    float w2 = fexp2(m2 - mM), w3 = fexp2(m3 - mM);
    float den = d0 * w0 + d1 * w1 + d2 * w2 + d3 * w3;
    float acc = a0 * w0 + a1 * w1 + a2 * w2 + a3 * w3;
    if (ld) agg2[(size_t)wid * 10 + l] = acc / (den + 1e-16f);
}

// ---------------- pool (+bias) + log_softmax; block per graph ----------------
__global__ void k_pool_final(const float* __restrict__ agg2, const float* __restrict__ b2,
                             const int* __restrict__ batch, float* __restrict__ out,
                             int N, int G) {
    int g = blockIdx.x;
    int lo = 0, hi = N;
    while (lo < hi) { int mid = (lo + hi) >> 1; if (batch[mid] < g) lo = mid + 1; else hi = mid; }
    int s = lo;
    lo = s; hi = N;
    while (lo < hi) { int mid = (lo + hi) >> 1; if (batch[mid] < g + 1) lo = mid + 1; else hi = mid; }
    int e = lo;
    int tid = threadIdx.x;
    float acc[10];
#pragma unroll
    for (int j = 0; j < 10; ++j) acc[j] = 0.f;
    for (int n = s + tid; n < e; n += 256) {
        const float* r = agg2 + (size_t)n * 10;
#pragma unroll
        for (int j = 0; j < 10; ++j) acc[j] += r[j];
    }
    __shared__ float red[256 * 10];
#pragma unroll
    for (int j = 0; j < 10; ++j) red[tid * 10 + j] = acc[j];
    __syncthreads();
    for (int st = 128; st > 0; st >>= 1) {
        if (tid < st)
#pragma unroll
            for (int j = 0; j < 10; ++j) red[tid * 10 + j] += red[(tid + st) * 10 + j];
        __syncthreads();
    }
    if (tid == 0) {
        int c = e - s;
        float v[10], m = -1e30f;
#pragma unroll
        for (int j = 0; j < 10; ++j) {
            v[j] = (c > 0) ? red[j] / (float)c + b2[j] : 0.f;
            m = fmaxf(m, v[j]);
        }
        float ssum = 0.f;
#pragma unroll
        for (int j = 0; j < 10; ++j) ssum += expf(v[j] - m);
        float ls = logf(ssum);
#pragma unroll
        for (int j = 0; j < 10; ++j) out[(size_t)g * 10 + j] = v[j] - m - ls;
    }
}

extern "C" void kernel_launch(void* const* d_in, const int* in_sizes, int n_in,
                              void* d_out, int out_size, void* d_ws, size_t ws_size,
                              hipStream_t stream) {
    const float* x     = (const float*)d_in[0];
    const int*   ei    = (const int*)d_in[1];
    const int*   batch = (const int*)d_in[2];
    const float* W1    = (const float*)d_in[3];
    const float* as1w  = (const float*)d_in[4];
    const float* ad1w  = (const float*)d_in[5];
    const float* b1    = (const float*)d_in[6];
    const float* W2    = (const float*)d_in[7];
    const float* as2w  = (const float*)d_in[8];
    const float* ad2w  = (const float*)d_in[9];
    const float* b2    = (const float*)d_in[10];

    const int N  = in_sizes[0] / 128;
    const int E  = in_sizes[1] / 2;
    const int G  = out_size / 10;
    const int* srcE = ei;
    const int* dstE = ei + E;

    auto cdiv = [](long long a, long long b) { return (int)((a + b - 1) / b); };
    const int NB = cdiv(E, CH);

    // ---- workspace layout ----
    size_t Nz = (size_t)N;
    unsigned short* h1b = (unsigned short*)d_ws;        // N*64 bf16
    float* agg2  = (float*)d_ws;                        // ALIAS: h1b dead after gather1
    unsigned short* asrc1b = h1b + Nz * 64;             // N*8 bf16
    float* adst1 = (float*)(asrc1b + Nz * 8);           // N*8 f32
    unsigned short* h2b = (unsigned short*)(adst1 + Nz * 8); // N*10 bf16
    unsigned short* asrc2b = h2b + Nz * 10;             // N bf16
    float* adst2 = (float*)(asrc2b + Nz + (Nz & 1));    // N f32 (align 4B)
    float* agg1  = adst2 + Nz;                          // N*64 f32
    int2*  pairs = (int2*)agg1;                         // ALIAS: dead before gather1 writes agg1
    int* cntA    = (int*)(agg1 + Nz * 64);              // N
    int* exclA   = cntA + Nz;                           // N
    int* srcsA   = exclA + Nz;                          // E
    int* bhA     = srcsA + E;                           // 512*NB
    int* pstartA = bhA + (size_t)512 * NB;              // 512*NB
    int* totalA  = pstartA + (size_t)512 * NB;          // 512
    int* boffA   = totalA + 512;                        // 512

    const int B = 256;

    // layer-1 GEMM (+alpha dots), 8 nodes/thread, bf16 h1
    k_gemm1<<<cdiv(N, 256), B, 0, stream>>>(x, W1, as1w, ad1w, h1b, asrc1b, adst1, N);

    // graph-bucket CSR build (no global atomics)
    k_bhist<<<NB, B, 0, stream>>>(dstE, batch, E, NB, G, bhA);
    k_mscan<<<512, 512, 0, stream>>>(bhA, NB, pstartA, totalA);
    k_scan_top<<<1, 1024, 0, stream>>>(totalA, G, boffA);
    k_bscatter<<<NB, B, 0, stream>>>(srcE, dstE, batch, boffA, pstartA, E, NB, G, pairs);
    k_csr_local<<<G, 512, 0, stream>>>(pairs, boffA, batch, E, N, G, cntA, exclA, srcsA);

    // layer 1 gather: 16 nodes/block (4/wave), 4ch/lane
    k_gather1<<<cdiv(N, 16), B, 0, stream>>>(srcsA, exclA, cntA, asrc1b, adst1, h1b, agg1, N);
    k_fin1<<<cdiv(N, B), B, 0, stream>>>(agg1, b1, W2, as2w, ad2w, h2b, asrc2b, adst2, N);

    // layer 2 gather (agg2 aliases dead h1b)
    k_gather2<<<cdiv(N, 16), B, 0, stream>>>(srcsA, exclA, cntA, asrc2b, adst2, h2b, agg2, N);

    // pool + log_softmax
    k_pool_final<<<G, B, 0, stream>>>(agg2, b2, batch, (float*)d_out, N, G);
}